// Round 1
// baseline (5880.162 us; speedup 1.0000x reference)
//
#include <hip/hip_runtime.h>

// ---------------------------------------------------------------------------
// GIN forward:  3x { agg = h + scatter_add(w_e * h[src] -> dst); h = relu(agg@W+b) }
// with layer 3 + global_add_pool algebraically fused:
//   out[g] = ( sum_{n in g} h2[n] + sum_{e: batch[dst_e]==g} w_e*h2[src_e] ) @ W3
//            + cnt[g]*b3
// ---------------------------------------------------------------------------

// ---- CSR build ------------------------------------------------------------
__global__ __launch_bounds__(256) void hist_kernel(const int* __restrict__ dst,
                                                   int* __restrict__ deg, int E_) {
    int e = blockIdx.x * 256 + threadIdx.x;
    if (e < E_) atomicAdd(&deg[dst[e]], 1);
}

__global__ __launch_bounds__(1024) void scan_kernel(int* __restrict__ rp,
                                                    int* __restrict__ cursor, int n) {
    __shared__ int sdata[1024];
    __shared__ int s_off;
    if (threadIdx.x == 0) s_off = 0;
    __syncthreads();
    for (int base = 0; base < n; base += 4096) {
        int i0 = base + threadIdx.x * 4;
        int v[4];
#pragma unroll
        for (int j = 0; j < 4; j++) v[j] = (i0 + j < n) ? rp[i0 + j] : 0;
        int s = v[0] + v[1] + v[2] + v[3];
        sdata[threadIdx.x] = s;
        __syncthreads();
        for (int ofs = 1; ofs < 1024; ofs <<= 1) {
            int t = (threadIdx.x >= ofs) ? sdata[threadIdx.x - ofs] : 0;
            __syncthreads();
            sdata[threadIdx.x] += t;
            __syncthreads();
        }
        int incl  = sdata[threadIdx.x];
        int total = sdata[1023];
        int excl  = s_off + incl - s;
#pragma unroll
        for (int j = 0; j < 4; j++) {
            if (i0 + j < n) { rp[i0 + j] = excl; cursor[i0 + j] = excl; }
            excl += v[j];
        }
        __syncthreads();
        if (threadIdx.x == 0) s_off += total;
        __syncthreads();
    }
    if (threadIdx.x == 0) rp[n] = s_off;
}

__global__ __launch_bounds__(256) void scatter_kernel(const int* __restrict__ src,
                                                      const int* __restrict__ dst,
                                                      const float* __restrict__ ew,
                                                      int* __restrict__ cursor,
                                                      int* __restrict__ csr_src,
                                                      float* __restrict__ csr_w, int E_) {
    int e = blockIdx.x * 256 + threadIdx.x;
    if (e >= E_) return;
    int d = dst[e];
    int p = atomicAdd(&cursor[d], 1);
    csr_src[p] = src[e];
    csr_w[p]   = ew[e];
}

// ---- per-node aggregation: Out[n] = H[n] + sum_{e in(n)} w_e * H[src_e] ----
// one 64-lane wave per node, lane k owns features [2k, 2k+1]
__global__ __launch_bounds__(256) void aggregate_kernel(const float* __restrict__ H,
                                                        const int* __restrict__ rp,
                                                        const int* __restrict__ csr_src,
                                                        const float* __restrict__ csr_w,
                                                        float* __restrict__ Out, int n) {
    int node = blockIdx.x * 4 + (threadIdx.x >> 6);
    int lane = threadIdx.x & 63;
    if (node >= n) return;
    const float2* H2 = (const float2*)H;
    float2 acc = H2[(size_t)node * 64 + lane];
    int e0 = rp[node], e1 = rp[node + 1];
    for (int e = e0; e < e1; e++) {
        int   s  = csr_src[e];
        float wt = csr_w[e];
        float2 v = H2[(size_t)s * 64 + lane];
        acc.x += wt * v.x;
        acc.y += wt * v.y;
    }
    ((float2*)Out)[(size_t)node * 64 + lane] = acc;
}

// ---- GEMM: Out[N,128] = relu(A[N,128] @ W[128,128] + b) --------------------
// 64x64 tile, W panel + padded A half-panel in LDS, 4x4 microtile
__global__ __launch_bounds__(256) void gemm128_bias_relu(const float* __restrict__ A,
                                                         const float* __restrict__ W,
                                                         const float* __restrict__ bias,
                                                         float* __restrict__ Out, int nrows) {
    __shared__ float Ws[128 * 64];   // [k][c] within 64-col window
    __shared__ float As[64 * 68];    // [r][k-half], +4 pad breaks bank conflict
    const int tid  = threadIdx.x;
    const int row0 = blockIdx.x * 64;
    const int col0 = blockIdx.y * 64;

    {   // stage W panel once
        int c4 = (tid & 15) * 4;
        int kr = tid >> 4;
#pragma unroll
        for (int it = 0; it < 8; ++it, kr += 16)
            *(float4*)(&Ws[kr * 64 + c4]) = *(const float4*)(&W[kr * 128 + col0 + c4]);
    }

    const int ty = tid >> 4, tx = tid & 15;
    const int rb = ty * 4, cb = tx * 4;
    float acc[4][4];
#pragma unroll
    for (int i = 0; i < 4; i++)
#pragma unroll
        for (int j = 0; j < 4; j++) acc[i][j] = 0.f;

#pragma unroll
    for (int kk = 0; kk < 128; kk += 64) {
        __syncthreads();
        {   // stage A half-K panel
            int c4 = (tid & 15) * 4;
            int r  = tid >> 4;
#pragma unroll
            for (int it = 0; it < 4; ++it, r += 16) {
                int grow = row0 + r;
                float4 v;
                if (grow < nrows) v = *(const float4*)(&A[(size_t)grow * 128 + kk + c4]);
                else { v.x = v.y = v.z = v.w = 0.f; }
                *(float4*)(&As[r * 68 + c4]) = v;
            }
        }
        __syncthreads();
#pragma unroll
        for (int k4 = 0; k4 < 16; ++k4) {
            float4 a0 = *(const float4*)(&As[(rb + 0) * 68 + k4 * 4]);
            float4 a1 = *(const float4*)(&As[(rb + 1) * 68 + k4 * 4]);
            float4 a2 = *(const float4*)(&As[(rb + 2) * 68 + k4 * 4]);
            float4 a3 = *(const float4*)(&As[(rb + 3) * 68 + k4 * 4]);
            float4 w0 = *(const float4*)(&Ws[(kk + k4 * 4 + 0) * 64 + cb]);
            float4 w1 = *(const float4*)(&Ws[(kk + k4 * 4 + 1) * 64 + cb]);
            float4 w2 = *(const float4*)(&Ws[(kk + k4 * 4 + 2) * 64 + cb]);
            float4 w3 = *(const float4*)(&Ws[(kk + k4 * 4 + 3) * 64 + cb]);
#define ACC_ROW(i, av)                                                   \
            acc[i][0] += av.x * w0.x + av.y * w1.x + av.z * w2.x + av.w * w3.x; \
            acc[i][1] += av.x * w0.y + av.y * w1.y + av.z * w2.y + av.w * w3.y; \
            acc[i][2] += av.x * w0.z + av.y * w1.z + av.z * w2.z + av.w * w3.z; \
            acc[i][3] += av.x * w0.w + av.y * w1.w + av.z * w2.w + av.w * w3.w;
            ACC_ROW(0, a0)
            ACC_ROW(1, a1)
            ACC_ROW(2, a2)
            ACC_ROW(3, a3)
#undef ACC_ROW
        }
    }

    float4 bv = *(const float4*)(&bias[col0 + cb]);
#pragma unroll
    for (int i = 0; i < 4; i++) {
        int grow = row0 + rb + i;
        if (grow < nrows) {
            float4 o;
            o.x = fmaxf(acc[i][0] + bv.x, 0.f);
            o.y = fmaxf(acc[i][1] + bv.y, 0.f);
            o.z = fmaxf(acc[i][2] + bv.z, 0.f);
            o.w = fmaxf(acc[i][3] + bv.w, 0.f);
            *(float4*)(&Out[(size_t)grow * 128 + col0 + cb]) = o;
        }
    }
}

// ---- layer-3 pooled path ---------------------------------------------------
__global__ __launch_bounds__(256) void graph_count(const int* __restrict__ batch,
                                                   int* __restrict__ cnt, int n) {
    int t  = blockIdx.x * 256 + threadIdx.x;
    int i0 = t * 16;
    if (i0 >= n) return;
    int end = min(i0 + 16, n);
    int g = batch[i0], c = 0;
    for (int i = i0; i < end; i++) {
        int gi = batch[i];
        if (gi != g) { atomicAdd(&cnt[g], c); g = gi; c = 0; }
        c++;
    }
    atomicAdd(&cnt[g], c);
}

// P[g][k] += sum_{n in g} H[n][k]   (batch is sorted -> run-length flush)
__global__ __launch_bounds__(128) void pool_nodes(const float* __restrict__ H,
                                                  const int* __restrict__ batch,
                                                  float* __restrict__ P, int n) {
    int k     = threadIdx.x;
    int start = blockIdx.x * 256;
    int end   = min(start + 256, n);
    float acc = 0.f;
    int gcur  = batch[start];
    for (int i = start; i < end; i++) {
        int g = batch[i];
        if (g != gcur) { atomicAdd(&P[gcur * 128 + k], acc); acc = 0.f; gcur = g; }
        acc += H[(size_t)i * 128 + k];
    }
    atomicAdd(&P[gcur * 128 + k], acc);
}

// P[g][k] += sum_{e: batch[dst_e]==g} w_e * H[src_e][k]   (LDS accumulator)
__global__ __launch_bounds__(256) void pool_edges(const float* __restrict__ H,
                                                  const int* __restrict__ src,
                                                  const int* __restrict__ dst,
                                                  const float* __restrict__ ew,
                                                  const int* __restrict__ batch,
                                                  float* __restrict__ P, int E_) {
    __shared__ float Pl[64 * 128];
    for (int i = threadIdx.x; i < 64 * 128; i += 256) Pl[i] = 0.f;
    __syncthreads();
    int k    = threadIdx.x & 127;
    int half = threadIdx.x >> 7;
    int per  = (E_ + gridDim.x - 1) / gridDim.x;
    int e0   = blockIdx.x * per;
    int e1   = min(e0 + per, E_);
    for (int e = e0 + half; e < e1; e += 2) {
        int   s  = src[e];
        float wt = ew[e];
        int   g  = batch[dst[e]];
        float v  = wt * H[(size_t)s * 128 + k];
        atomicAdd(&Pl[g * 128 + k], v);
    }
    __syncthreads();
    for (int i = threadIdx.x; i < 64 * 128; i += 256) atomicAdd(&P[i], Pl[i]);
}

// out[g][c] = sum_k P[g][k]*W3[k][c] + cnt[g]*b3[c]
__global__ __launch_bounds__(256) void final_kernel(const float* __restrict__ P,
                                                    const float* __restrict__ W3,
                                                    const float* __restrict__ b3,
                                                    const int* __restrict__ cnt,
                                                    float* __restrict__ out, int total) {
    int idx = blockIdx.x * 256 + threadIdx.x;
    if (idx >= total) return;
    int g = idx / 40, c = idx % 40;
    float acc = (float)cnt[g] * b3[c];
    for (int kk = 0; kk < 128; kk++) acc += P[g * 128 + kk] * W3[kk * 40 + c];
    out[idx] = acc;
}

// ---------------------------------------------------------------------------
extern "C" void kernel_launch(void* const* d_in, const int* in_sizes, int n_in,
                              void* d_out, int out_size, void* d_ws, size_t ws_size,
                              hipStream_t stream) {
    const float* x     = (const float*)d_in[0];
    const int*   ei    = (const int*)d_in[1];
    const float* ew    = (const float*)d_in[2];
    const int*   batch = (const int*)d_in[3];
    const float* W1    = (const float*)d_in[4];
    const float* b1    = (const float*)d_in[5];
    const float* W2    = (const float*)d_in[6];
    const float* b2    = (const float*)d_in[7];
    const float* W3    = (const float*)d_in[8];
    const float* b3    = (const float*)d_in[9];
    float*       out   = (float*)d_out;

    const int E_ = in_sizes[2];   // edge_weight length
    const int N_ = in_sizes[3];   // batch length
    const int* srcp = ei;
    const int* dstp = ei + E_;

    char*  w   = (char*)d_ws;
    size_t off = 0;
    auto take = [&](size_t bytes) -> char* {
        char* p = w + off;
        off = (off + bytes + 255) & ~(size_t)255;
        return p;
    };
    float* A       = (float*)take((size_t)N_ * 128 * 4);
    float* B       = (float*)take((size_t)N_ * 128 * 4);
    int*   rp      = (int*)take((size_t)(N_ + 1) * 4);
    int*   cursor  = (int*)take((size_t)N_ * 4);
    int*   csr_src = (int*)take((size_t)E_ * 4);
    float* csr_w   = (float*)take((size_t)E_ * 4);
    float* P       = (float*)take(64 * 128 * 4);
    int*   cnt     = (int*)take(64 * 4);
    (void)ws_size; (void)n_in;

    // CSR by destination
    hipMemsetAsync(rp, 0, (size_t)(N_ + 1) * 4, stream);
    hist_kernel<<<(E_ + 255) / 256, 256, 0, stream>>>(dstp, rp, E_);
    scan_kernel<<<1, 1024, 0, stream>>>(rp, cursor, N_);
    scatter_kernel<<<(E_ + 255) / 256, 256, 0, stream>>>(srcp, dstp, ew, cursor,
                                                         csr_src, csr_w, E_);

    dim3 ggrid((N_ + 63) / 64, 2);
    // layer 1
    aggregate_kernel<<<(N_ + 3) / 4, 256, 0, stream>>>(x, rp, csr_src, csr_w, A, N_);
    gemm128_bias_relu<<<ggrid, 256, 0, stream>>>(A, W1, b1, B, N_);
    // layer 2
    aggregate_kernel<<<(N_ + 3) / 4, 256, 0, stream>>>(B, rp, csr_src, csr_w, A, N_);
    gemm128_bias_relu<<<ggrid, 256, 0, stream>>>(A, W2, b2, B, N_);

    // layer 3 fused with global_add_pool
    hipMemsetAsync(P, 0, 64 * 128 * 4, stream);
    hipMemsetAsync(cnt, 0, 64 * 4, stream);
    graph_count<<<((N_ + 15) / 16 + 255) / 256, 256, 0, stream>>>(batch, cnt, N_);
    pool_nodes<<<(N_ + 255) / 256, 128, 0, stream>>>(B, batch, P, N_);
    pool_edges<<<256, 256, 0, stream>>>(B, srcp, dstp, ew, batch, P, E_);
    final_kernel<<<(out_size + 255) / 256, 256, 0, stream>>>(P, W3, b3, cnt, out, out_size);
}

// Round 2
// 4005.515 us; speedup vs baseline: 1.4680x; 1.4680x over previous
//
#include <hip/hip_runtime.h>

// ---------------------------------------------------------------------------
// GIN forward:  3x { agg = h + scatter_add(w_e * h[src] -> dst); h = relu(agg@W+b) }
// Layer 3 + global_add_pool fused algebraically:
//   out[g] = pool_g(h2 + agg3) @ W3 + cnt[g]*b3
// where agg3 comes from the same CSR aggregate as layers 1/2 (no edge-pool kernel).
// ---------------------------------------------------------------------------

// ---- CSR build ------------------------------------------------------------
__global__ __launch_bounds__(256) void hist_kernel(const int* __restrict__ dst,
                                                   int* __restrict__ deg, int E_) {
    int e = blockIdx.x * 256 + threadIdx.x;
    if (e < E_) atomicAdd(&deg[dst[e]], 1);
}

// 3-phase single-block scan: per-thread serial sum, 1024-ladder, serial writeback.
__global__ __launch_bounds__(1024) void scan_kernel(int* __restrict__ rp,
                                                    int* __restrict__ cursor, int n) {
    __shared__ int sums[1024];
    const int tid = threadIdx.x;
    const int per = (n + 1023) / 1024;
    const int i0 = tid * per, i1 = min(i0 + per, n);
    int s = 0;
    for (int i = i0; i < i1; i++) s += rp[i];
    sums[tid] = s;
    __syncthreads();
    for (int ofs = 1; ofs < 1024; ofs <<= 1) {
        int t = (tid >= ofs) ? sums[tid - ofs] : 0;
        __syncthreads();
        sums[tid] += t;
        __syncthreads();
    }
    int excl = sums[tid] - s;   // exclusive prefix of this thread's range
    for (int i = i0; i < i1; i++) {
        int v = rp[i];
        rp[i] = excl;
        cursor[i] = excl;
        excl += v;
    }
    if (tid == 1023) rp[n] = sums[1023];
}

__global__ __launch_bounds__(256) void scatter_kernel(const int* __restrict__ src,
                                                      const int* __restrict__ dst,
                                                      const float* __restrict__ ew,
                                                      int* __restrict__ cursor,
                                                      int* __restrict__ csr_src,
                                                      float* __restrict__ csr_w, int E_) {
    int e = blockIdx.x * 256 + threadIdx.x;
    if (e >= E_) return;
    int d = dst[e];
    int p = atomicAdd(&cursor[d], 1);
    csr_src[p] = src[e];
    csr_w[p]   = ew[e];
}

// ---- per-node aggregation: Out[n] = H[n] + sum_{e in(n)} w_e * H[src_e] ----
// One wave per node; lanes cooperatively load (src,w) pairs, broadcast by shfl,
// so per-edge gathers are independent and pipeline under vmcnt.
__global__ __launch_bounds__(256) void aggregate_kernel(const float* __restrict__ H,
                                                        const int* __restrict__ rp,
                                                        const int* __restrict__ csr_src,
                                                        const float* __restrict__ csr_w,
                                                        float* __restrict__ Out, int n) {
    int node = blockIdx.x * 4 + (threadIdx.x >> 6);
    int lane = threadIdx.x & 63;
    if (node >= n) return;
    const float2* H2 = (const float2*)H;
    float2 acc = H2[(size_t)node * 64 + lane];
    const int e0 = rp[node], e1 = rp[node + 1];
    for (int base = e0; base < e1; base += 64) {
        int cnt = min(64, e1 - base);
        int   sv = 0;
        float wv = 0.f;
        if (base + lane < e1) {
            sv = csr_src[base + lane];
            wv = csr_w[base + lane];
        }
        for (int j = 0; j < cnt; j++) {
            int   sj = __shfl(sv, j);
            float wj = __shfl(wv, j);
            float2 v = H2[(size_t)sj * 64 + lane];
            acc.x += wj * v.x;
            acc.y += wj * v.y;
        }
    }
    ((float2*)Out)[(size_t)node * 64 + lane] = acc;
}

// ---- GEMM: Out[N,128] = relu(A[N,128] @ W[128,128] + b) --------------------
// 64x64 tile, W panel + padded A half-panel in LDS, 4x4 microtile
__global__ __launch_bounds__(256) void gemm128_bias_relu(const float* __restrict__ A,
                                                         const float* __restrict__ W,
                                                         const float* __restrict__ bias,
                                                         float* __restrict__ Out, int nrows) {
    __shared__ float Ws[128 * 64];   // [k][c] within 64-col window
    __shared__ float As[64 * 68];    // [r][k-half], +4 pad breaks bank conflict
    const int tid  = threadIdx.x;
    const int row0 = blockIdx.x * 64;
    const int col0 = blockIdx.y * 64;

    {   // stage W panel once
        int c4 = (tid & 15) * 4;
        int kr = tid >> 4;
#pragma unroll
        for (int it = 0; it < 8; ++it, kr += 16)
            *(float4*)(&Ws[kr * 64 + c4]) = *(const float4*)(&W[kr * 128 + col0 + c4]);
    }

    const int ty = tid >> 4, tx = tid & 15;
    const int rb = ty * 4, cb = tx * 4;
    float acc[4][4];
#pragma unroll
    for (int i = 0; i < 4; i++)
#pragma unroll
        for (int j = 0; j < 4; j++) acc[i][j] = 0.f;

#pragma unroll
    for (int kk = 0; kk < 128; kk += 64) {
        __syncthreads();
        {   // stage A half-K panel
            int c4 = (tid & 15) * 4;
            int r  = tid >> 4;
#pragma unroll
            for (int it = 0; it < 4; ++it, r += 16) {
                int grow = row0 + r;
                float4 v;
                if (grow < nrows) v = *(const float4*)(&A[(size_t)grow * 128 + kk + c4]);
                else { v.x = v.y = v.z = v.w = 0.f; }
                *(float4*)(&As[r * 68 + c4]) = v;
            }
        }
        __syncthreads();
#pragma unroll
        for (int k4 = 0; k4 < 16; ++k4) {
            float4 a0 = *(const float4*)(&As[(rb + 0) * 68 + k4 * 4]);
            float4 a1 = *(const float4*)(&As[(rb + 1) * 68 + k4 * 4]);
            float4 a2 = *(const float4*)(&As[(rb + 2) * 68 + k4 * 4]);
            float4 a3 = *(const float4*)(&As[(rb + 3) * 68 + k4 * 4]);
            float4 w0 = *(const float4*)(&Ws[(kk + k4 * 4 + 0) * 64 + cb]);
            float4 w1 = *(const float4*)(&Ws[(kk + k4 * 4 + 1) * 64 + cb]);
            float4 w2 = *(const float4*)(&Ws[(kk + k4 * 4 + 2) * 64 + cb]);
            float4 w3 = *(const float4*)(&Ws[(kk + k4 * 4 + 3) * 64 + cb]);
#define ACC_ROW(i, av)                                                   \
            acc[i][0] += av.x * w0.x + av.y * w1.x + av.z * w2.x + av.w * w3.x; \
            acc[i][1] += av.x * w0.y + av.y * w1.y + av.z * w2.y + av.w * w3.y; \
            acc[i][2] += av.x * w0.z + av.y * w1.z + av.z * w2.z + av.w * w3.z; \
            acc[i][3] += av.x * w0.w + av.y * w1.w + av.z * w2.w + av.w * w3.w;
            ACC_ROW(0, a0)
            ACC_ROW(1, a1)
            ACC_ROW(2, a2)
            ACC_ROW(3, a3)
#undef ACC_ROW
        }
    }

    float4 bv = *(const float4*)(&bias[col0 + cb]);
#pragma unroll
    for (int i = 0; i < 4; i++) {
        int grow = row0 + rb + i;
        if (grow < nrows) {
            float4 o;
            o.x = fmaxf(acc[i][0] + bv.x, 0.f);
            o.y = fmaxf(acc[i][1] + bv.y, 0.f);
            o.z = fmaxf(acc[i][2] + bv.z, 0.f);
            o.w = fmaxf(acc[i][3] + bv.w, 0.f);
            *(float4*)(&Out[(size_t)grow * 128 + col0 + cb]) = o;
        }
    }
}

// ---- pooling ---------------------------------------------------------------
__global__ __launch_bounds__(256) void graph_count(const int* __restrict__ batch,
                                                   int* __restrict__ cnt, int n) {
    int t  = blockIdx.x * 256 + threadIdx.x;
    int i0 = t * 16;
    if (i0 >= n) return;
    int end = min(i0 + 16, n);
    int g = batch[i0], c = 0;
    for (int i = i0; i < end; i++) {
        int gi = batch[i];
        if (gi != g) { atomicAdd(&cnt[g], c); g = gi; c = 0; }
        c++;
    }
    atomicAdd(&cnt[g], c);
}

// P[g][k] += sum_{n in g} H[n][k]   (batch is sorted -> run-length flush)
__global__ __launch_bounds__(128) void pool_nodes(const float* __restrict__ H,
                                                  const int* __restrict__ batch,
                                                  float* __restrict__ P, int n) {
    int k     = threadIdx.x;
    int start = blockIdx.x * 256;
    int end   = min(start + 256, n);
    float acc = 0.f;
    int gcur  = batch[start];
    for (int i = start; i < end; i++) {
        int g = batch[i];
        if (g != gcur) { atomicAdd(&P[gcur * 128 + k], acc); acc = 0.f; gcur = g; }
        acc += H[(size_t)i * 128 + k];
    }
    atomicAdd(&P[gcur * 128 + k], acc);
}

// out[g][c] = sum_k P[g][k]*W3[k][c] + cnt[g]*b3[c]
__global__ __launch_bounds__(256) void final_kernel(const float* __restrict__ P,
                                                    const float* __restrict__ W3,
                                                    const float* __restrict__ b3,
                                                    const int* __restrict__ cnt,
                                                    float* __restrict__ out, int total) {
    int idx = blockIdx.x * 256 + threadIdx.x;
    if (idx >= total) return;
    int g = idx / 40, c = idx % 40;
    float acc = (float)cnt[g] * b3[c];
    for (int kk = 0; kk < 128; kk++) acc += P[g * 128 + kk] * W3[kk * 40 + c];
    out[idx] = acc;
}

// ---------------------------------------------------------------------------
extern "C" void kernel_launch(void* const* d_in, const int* in_sizes, int n_in,
                              void* d_out, int out_size, void* d_ws, size_t ws_size,
                              hipStream_t stream) {
    const float* x     = (const float*)d_in[0];
    const int*   ei    = (const int*)d_in[1];
    const float* ew    = (const float*)d_in[2];
    const int*   batch = (const int*)d_in[3];
    const float* W1    = (const float*)d_in[4];
    const float* b1    = (const float*)d_in[5];
    const float* W2    = (const float*)d_in[6];
    const float* b2    = (const float*)d_in[7];
    const float* W3    = (const float*)d_in[8];
    const float* b3    = (const float*)d_in[9];
    float*       out   = (float*)d_out;

    const int E_ = in_sizes[2];   // edge_weight length
    const int N_ = in_sizes[3];   // batch length
    const int* srcp = ei;
    const int* dstp = ei + E_;

    char*  w   = (char*)d_ws;
    size_t off = 0;
    auto take = [&](size_t bytes) -> char* {
        char* p = w + off;
        off = (off + bytes + 255) & ~(size_t)255;
        return p;
    };
    float* A       = (float*)take((size_t)N_ * 128 * 4);
    float* B       = (float*)take((size_t)N_ * 128 * 4);
    int*   rp      = (int*)take((size_t)(N_ + 1) * 4);
    int*   cursor  = (int*)take((size_t)N_ * 4);
    int*   csr_src = (int*)take((size_t)E_ * 4);
    float* csr_w   = (float*)take((size_t)E_ * 4);
    float* P       = (float*)take(64 * 128 * 4);
    int*   cnt     = (int*)take(64 * 4);
    (void)ws_size; (void)n_in;

    // CSR by destination
    hipMemsetAsync(rp, 0, (size_t)(N_ + 1) * 4, stream);
    hist_kernel<<<(E_ + 255) / 256, 256, 0, stream>>>(dstp, rp, E_);
    scan_kernel<<<1, 1024, 0, stream>>>(rp, cursor, N_);
    scatter_kernel<<<(E_ + 255) / 256, 256, 0, stream>>>(srcp, dstp, ew, cursor,
                                                         csr_src, csr_w, E_);

    dim3 ggrid((N_ + 63) / 64, 2);
    // layer 1
    aggregate_kernel<<<(N_ + 3) / 4, 256, 0, stream>>>(x, rp, csr_src, csr_w, A, N_);
    gemm128_bias_relu<<<ggrid, 256, 0, stream>>>(A, W1, b1, B, N_);
    // layer 2
    aggregate_kernel<<<(N_ + 3) / 4, 256, 0, stream>>>(B, rp, csr_src, csr_w, A, N_);
    gemm128_bias_relu<<<ggrid, 256, 0, stream>>>(A, W2, b2, B, N_);

    // layer 3 fused with global_add_pool:
    //   out[g] = pool_g(h2 + agg3) @ W3 + cnt[g]*b3
    aggregate_kernel<<<(N_ + 3) / 4, 256, 0, stream>>>(B, rp, csr_src, csr_w, A, N_);
    hipMemsetAsync(P, 0, 64 * 128 * 4, stream);
    hipMemsetAsync(cnt, 0, 64 * 4, stream);
    graph_count<<<((N_ + 15) / 16 + 255) / 256, 256, 0, stream>>>(batch, cnt, N_);
    pool_nodes<<<(N_ + 255) / 256, 128, 0, stream>>>(A, batch, P, N_);
    final_kernel<<<(out_size + 255) / 256, 256, 0, stream>>>(P, W3, b3, cnt, out, out_size);
}

// Round 3
// 1043.215 us; speedup vs baseline: 5.6366x; 3.8396x over previous
//
#include <hip/hip_runtime.h>

// ---------------------------------------------------------------------------
// GIN forward:  3x { agg = h + scatter_add(w_e * h[src] -> dst); h = relu(agg@W+b) }
// Layer 3 + global_add_pool fused algebraically:
//   out[g] = pool_g(h2 + agg3) @ W3 + cnt[g]*b3
// ---------------------------------------------------------------------------

// ---- CSR build ------------------------------------------------------------
__global__ __launch_bounds__(256) void hist_kernel(const int* __restrict__ dst,
                                                   int* __restrict__ deg, int E_) {
    int e = blockIdx.x * 256 + threadIdx.x;
    if (e < E_) atomicAdd(&deg[dst[e]], 1);
}

// 3-phase single-block scan: per-thread serial sum, 1024-ladder, serial writeback.
__global__ __launch_bounds__(1024) void scan_kernel(int* __restrict__ rp,
                                                    int* __restrict__ cursor, int n) {
    __shared__ int sums[1024];
    const int tid = threadIdx.x;
    const int per = (n + 1023) / 1024;
    const int i0 = tid * per, i1 = min(i0 + per, n);
    int s = 0;
    for (int i = i0; i < i1; i++) s += rp[i];
    sums[tid] = s;
    __syncthreads();
    for (int ofs = 1; ofs < 1024; ofs <<= 1) {
        int t = (tid >= ofs) ? sums[tid - ofs] : 0;
        __syncthreads();
        sums[tid] += t;
        __syncthreads();
    }
    int excl = sums[tid] - s;   // exclusive prefix of this thread's range
    for (int i = i0; i < i1; i++) {
        int v = rp[i];
        rp[i] = excl;
        cursor[i] = excl;
        excl += v;
    }
    if (tid == 1023) rp[n] = sums[1023];
}

__global__ __launch_bounds__(256) void scatter_kernel(const int* __restrict__ src,
                                                      const int* __restrict__ dst,
                                                      const float* __restrict__ ew,
                                                      int* __restrict__ cursor,
                                                      int* __restrict__ csr_src,
                                                      float* __restrict__ csr_w, int E_) {
    int e = blockIdx.x * 256 + threadIdx.x;
    if (e >= E_) return;
    int d = dst[e];
    int p = atomicAdd(&cursor[d], 1);
    csr_src[p] = src[e];
    csr_w[p]   = ew[e];
}

// ---- per-node aggregation: Out[n] = H[n] + sum_{e in(n)} w_e * H[src_e] ----
// One wave per node; lanes cooperatively load (src,w) pairs, broadcast by shfl,
// so per-edge gathers are independent and pipeline under vmcnt.
__global__ __launch_bounds__(256) void aggregate_kernel(const float* __restrict__ H,
                                                        const int* __restrict__ rp,
                                                        const int* __restrict__ csr_src,
                                                        const float* __restrict__ csr_w,
                                                        float* __restrict__ Out, int n) {
    int node = blockIdx.x * 4 + (threadIdx.x >> 6);
    int lane = threadIdx.x & 63;
    if (node >= n) return;
    const float2* H2 = (const float2*)H;
    float2 acc = H2[(size_t)node * 64 + lane];
    const int e0 = rp[node], e1 = rp[node + 1];
    for (int base = e0; base < e1; base += 64) {
        int cnt = min(64, e1 - base);
        int   sv = 0;
        float wv = 0.f;
        if (base + lane < e1) {
            sv = csr_src[base + lane];
            wv = csr_w[base + lane];
        }
        for (int j = 0; j < cnt; j++) {
            int   sj = __shfl(sv, j);
            float wj = __shfl(wv, j);
            float2 v = H2[(size_t)sj * 64 + lane];
            acc.x += wj * v.x;
            acc.y += wj * v.y;
        }
    }
    ((float2*)Out)[(size_t)node * 64 + lane] = acc;
}

// ---- GEMM: Out[N,128] = relu(A[N,128] @ W[128,128] + b) --------------------
// 64-row x 64-col tile, K=128 staged once (no k-outer loop). 4x4 microtile.
// #pragma unroll 1 on the k loop: keeps ~65 live VGPRs, no spill (R2 lesson:
// full unroll hoisted 128 float4 LDS reads -> 256 VGPR -> 5.7GB scratch traffic).
__global__ __launch_bounds__(256) void gemm128_bias_relu(const float* __restrict__ A,
                                                         const float* __restrict__ W,
                                                         const float* __restrict__ bias,
                                                         float* __restrict__ Out, int nrows) {
    __shared__ float Ws[128 * 64];    // [k][c-local]
    __shared__ float As[64 * 132];    // [r][k], +4 pad
    const int tid  = threadIdx.x;
    const int row0 = blockIdx.x * 64;
    const int col0 = blockIdx.y * 64;

    {   // stage W panel: 128x64
        int c4 = (tid & 15) * 4;
        int kr = tid >> 4;
#pragma unroll
        for (int it = 0; it < 8; ++it, kr += 16)
            *(float4*)(&Ws[kr * 64 + c4]) = *(const float4*)(&W[kr * 128 + col0 + c4]);
    }
    {   // stage A tile: 64x128
        int c4 = (tid & 31) * 4;
        int r  = tid >> 5;
#pragma unroll
        for (int it = 0; it < 8; ++it, r += 8) {
            int grow = row0 + r;
            float4 v = {0.f, 0.f, 0.f, 0.f};
            if (grow < nrows) v = *(const float4*)(&A[(size_t)grow * 128 + c4]);
            *(float4*)(&As[r * 132 + c4]) = v;
        }
    }
    __syncthreads();

    const int rb = (tid >> 4) * 4, cb = (tid & 15) * 4;
    float acc[4][4];
#pragma unroll
    for (int i = 0; i < 4; i++)
#pragma unroll
        for (int j = 0; j < 4; j++) acc[i][j] = 0.f;

#pragma unroll 1
    for (int k = 0; k < 128; k += 4) {
        float4 a0 = *(const float4*)(&As[(rb + 0) * 132 + k]);
        float4 a1 = *(const float4*)(&As[(rb + 1) * 132 + k]);
        float4 a2 = *(const float4*)(&As[(rb + 2) * 132 + k]);
        float4 a3 = *(const float4*)(&As[(rb + 3) * 132 + k]);
        float4 w0 = *(const float4*)(&Ws[(k + 0) * 64 + cb]);
        float4 w1 = *(const float4*)(&Ws[(k + 1) * 64 + cb]);
        float4 w2 = *(const float4*)(&Ws[(k + 2) * 64 + cb]);
        float4 w3 = *(const float4*)(&Ws[(k + 3) * 64 + cb]);
#define ACC_ROW(i, av)                                                   \
        acc[i][0] += av.x * w0.x + av.y * w1.x + av.z * w2.x + av.w * w3.x; \
        acc[i][1] += av.x * w0.y + av.y * w1.y + av.z * w2.y + av.w * w3.y; \
        acc[i][2] += av.x * w0.z + av.y * w1.z + av.z * w2.z + av.w * w3.z; \
        acc[i][3] += av.x * w0.w + av.y * w1.w + av.z * w2.w + av.w * w3.w;
        ACC_ROW(0, a0)
        ACC_ROW(1, a1)
        ACC_ROW(2, a2)
        ACC_ROW(3, a3)
#undef ACC_ROW
    }

    float4 bv = *(const float4*)(&bias[col0 + cb]);
#pragma unroll
    for (int i = 0; i < 4; i++) {
        int grow = row0 + rb + i;
        if (grow < nrows) {
            float4 o;
            o.x = fmaxf(acc[i][0] + bv.x, 0.f);
            o.y = fmaxf(acc[i][1] + bv.y, 0.f);
            o.z = fmaxf(acc[i][2] + bv.z, 0.f);
            o.w = fmaxf(acc[i][3] + bv.w, 0.f);
            *(float4*)(&Out[(size_t)grow * 128 + col0 + cb]) = o;
        }
    }
}

// ---- pooling ---------------------------------------------------------------
__global__ __launch_bounds__(256) void graph_count(const int* __restrict__ batch,
                                                   int* __restrict__ cnt, int n) {
    int t  = blockIdx.x * 256 + threadIdx.x;
    int i0 = t * 16;
    if (i0 >= n) return;
    int end = min(i0 + 16, n);
    int g = batch[i0], c = 0;
    for (int i = i0; i < end; i++) {
        int gi = batch[i];
        if (gi != g) { atomicAdd(&cnt[g], c); g = gi; c = 0; }
        c++;
    }
    atomicAdd(&cnt[g], c);
}

// P[g][k] += sum_{n in g} H[n][k]   (batch is sorted -> run-length flush)
__global__ __launch_bounds__(128) void pool_nodes(const float* __restrict__ H,
                                                  const int* __restrict__ batch,
                                                  float* __restrict__ P, int n) {
    int k     = threadIdx.x;
    int start = blockIdx.x * 256;
    int end   = min(start + 256, n);
    float acc = 0.f;
    int gcur  = batch[start];
    for (int i = start; i < end; i++) {
        int g = batch[i];
        if (g != gcur) { atomicAdd(&P[gcur * 128 + k], acc); acc = 0.f; gcur = g; }
        acc += H[(size_t)i * 128 + k];
    }
    atomicAdd(&P[gcur * 128 + k], acc);
}

// out[g][c] = sum_k P[g][k]*W3[k][c] + cnt[g]*b3[c]
__global__ __launch_bounds__(256) void final_kernel(const float* __restrict__ P,
                                                    const float* __restrict__ W3,
                                                    const float* __restrict__ b3,
                                                    const int* __restrict__ cnt,
                                                    float* __restrict__ out, int total) {
    int idx = blockIdx.x * 256 + threadIdx.x;
    if (idx >= total) return;
    int g = idx / 40, c = idx % 40;
    float acc = (float)cnt[g] * b3[c];
    for (int kk = 0; kk < 128; kk++) acc += P[g * 128 + kk] * W3[kk * 40 + c];
    out[idx] = acc;
}

// ---------------------------------------------------------------------------
extern "C" void kernel_launch(void* const* d_in, const int* in_sizes, int n_in,
                              void* d_out, int out_size, void* d_ws, size_t ws_size,
                              hipStream_t stream) {
    const float* x     = (const float*)d_in[0];
    const int*   ei    = (const int*)d_in[1];
    const float* ew    = (const float*)d_in[2];
    const int*   batch = (const int*)d_in[3];
    const float* W1    = (const float*)d_in[4];
    const float* b1    = (const float*)d_in[5];
    const float* W2    = (const float*)d_in[6];
    const float* b2    = (const float*)d_in[7];
    const float* W3    = (const float*)d_in[8];
    const float* b3    = (const float*)d_in[9];
    float*       out   = (float*)d_out;

    const int E_ = in_sizes[2];   // edge_weight length
    const int N_ = in_sizes[3];   // batch length
    const int* srcp = ei;
    const int* dstp = ei + E_;

    char*  w   = (char*)d_ws;
    size_t off = 0;
    auto take = [&](size_t bytes) -> char* {
        char* p = w + off;
        off = (off + bytes + 255) & ~(size_t)255;
        return p;
    };
    float* A       = (float*)take((size_t)N_ * 128 * 4);
    float* B       = (float*)take((size_t)N_ * 128 * 4);
    int*   rp      = (int*)take((size_t)(N_ + 1) * 4);
    int*   cursor  = (int*)take((size_t)N_ * 4);
    int*   csr_src = (int*)take((size_t)E_ * 4);
    float* csr_w   = (float*)take((size_t)E_ * 4);
    float* P       = (float*)take(64 * 128 * 4);
    int*   cnt     = (int*)take(64 * 4);
    (void)ws_size; (void)n_in;

    // CSR by destination
    hipMemsetAsync(rp, 0, (size_t)(N_ + 1) * 4, stream);
    hist_kernel<<<(E_ + 255) / 256, 256, 0, stream>>>(dstp, rp, E_);
    scan_kernel<<<1, 1024, 0, stream>>>(rp, cursor, N_);
    scatter_kernel<<<(E_ + 255) / 256, 256, 0, stream>>>(srcp, dstp, ew, cursor,
                                                         csr_src, csr_w, E_);

    dim3 ggrid((N_ + 63) / 64, 2);
    // layer 1
    aggregate_kernel<<<(N_ + 3) / 4, 256, 0, stream>>>(x, rp, csr_src, csr_w, A, N_);
    gemm128_bias_relu<<<ggrid, 256, 0, stream>>>(A, W1, b1, B, N_);
    // layer 2
    aggregate_kernel<<<(N_ + 3) / 4, 256, 0, stream>>>(B, rp, csr_src, csr_w, A, N_);
    gemm128_bias_relu<<<ggrid, 256, 0, stream>>>(A, W2, b2, B, N_);

    // layer 3 fused with global_add_pool:
    //   out[g] = pool_g(h2 + agg3) @ W3 + cnt[g]*b3
    aggregate_kernel<<<(N_ + 3) / 4, 256, 0, stream>>>(B, rp, csr_src, csr_w, A, N_);
    hipMemsetAsync(P, 0, 64 * 128 * 4, stream);
    hipMemsetAsync(cnt, 0, 64 * 4, stream);
    graph_count<<<((N_ + 15) / 16 + 255) / 256, 256, 0, stream>>>(batch, cnt, N_);
    pool_nodes<<<(N_ + 255) / 256, 128, 0, stream>>>(A, batch, P, N_);
    final_kernel<<<(out_size + 255) / 256, 256, 0, stream>>>(P, W3, b3, cnt, out, out_size);
}

// Round 4
// 826.274 us; speedup vs baseline: 7.1165x; 1.2626x over previous
//
#include <hip/hip_runtime.h>

// ---------------------------------------------------------------------------
// GIN forward:  3x { agg = h + scatter_add(w_e * h[src] -> dst); h = relu(agg@W+b) }
// Layer 3 + global_add_pool fused algebraically:
//   out[g] = pool_g(h2 + agg3) @ W3 + cnt[g]*b3
// ---------------------------------------------------------------------------

// ---- CSR build ------------------------------------------------------------
__global__ __launch_bounds__(256) void hist_kernel(const int* __restrict__ dst,
                                                   int* __restrict__ deg, int E_) {
    int e = blockIdx.x * 256 + threadIdx.x;
    if (e < E_) atomicAdd(&deg[dst[e]], 1);
}

// ---- 3-kernel parallel exclusive scan (R3: single-block scan was 233us,
// one CU busy; multi-block brings it to ~20us total) ------------------------
#define SCAN_T 256
#define SCAN_V 4
#define SCAN_BPB (SCAN_T * SCAN_V)   // 1024 elements per block

__global__ __launch_bounds__(SCAN_T) void scan_partials(const int* __restrict__ deg,
                                                        int* __restrict__ bsum, int n) {
    const int b = blockIdx.x, tid = threadIdx.x;
    const int i0 = b * SCAN_BPB + tid * SCAN_V;
    int s = 0;
    if (i0 + SCAN_V <= n) {
        int4 v = *(const int4*)(&deg[i0]);
        s = v.x + v.y + v.z + v.w;
    } else {
        for (int j = 0; j < SCAN_V; j++) if (i0 + j < n) s += deg[i0 + j];
    }
    __shared__ int sd[SCAN_T];
    sd[tid] = s;
    __syncthreads();
    for (int ofs = 1; ofs < SCAN_T; ofs <<= 1) {
        int t = (tid >= ofs) ? sd[tid - ofs] : 0;
        __syncthreads();
        sd[tid] += t;
        __syncthreads();
    }
    if (tid == SCAN_T - 1) bsum[b] = sd[tid];
}

__global__ __launch_bounds__(1024) void scan_blocksums(int* __restrict__ bsum, int nb) {
    __shared__ int sd[1024];
    const int tid = threadIdx.x;
    int v = (tid < nb) ? bsum[tid] : 0;
    sd[tid] = v;
    __syncthreads();
    for (int ofs = 1; ofs < 1024; ofs <<= 1) {
        int t = (tid >= ofs) ? sd[tid - ofs] : 0;
        __syncthreads();
        sd[tid] += t;
        __syncthreads();
    }
    if (tid < nb) bsum[tid] = sd[tid] - v;   // exclusive
}

__global__ __launch_bounds__(SCAN_T) void scan_apply(int* __restrict__ rp,
                                                     int* __restrict__ cursor,
                                                     const int* __restrict__ bsum,
                                                     int n, int total) {
    const int b = blockIdx.x, tid = threadIdx.x;
    const int i0 = b * SCAN_BPB + tid * SCAN_V;
    int v[SCAN_V];
    int s = 0;
    if (i0 + SCAN_V <= n) {
        int4 t = *(const int4*)(&rp[i0]);
        v[0] = t.x; v[1] = t.y; v[2] = t.z; v[3] = t.w;
        s = v[0] + v[1] + v[2] + v[3];
    } else {
        for (int j = 0; j < SCAN_V; j++) { v[j] = (i0 + j < n) ? rp[i0 + j] : 0; s += v[j]; }
    }
    __shared__ int sd[SCAN_T];
    sd[tid] = s;
    __syncthreads();
    for (int ofs = 1; ofs < SCAN_T; ofs <<= 1) {
        int t = (tid >= ofs) ? sd[tid - ofs] : 0;
        __syncthreads();
        sd[tid] += t;
        __syncthreads();
    }
    int excl = bsum[b] + sd[tid] - s;
    for (int j = 0; j < SCAN_V; j++) {
        if (i0 + j < n) { rp[i0 + j] = excl; cursor[i0 + j] = excl; }
        excl += v[j];
    }
    if (b == 0 && tid == 0) rp[n] = total;
}

__global__ __launch_bounds__(256) void scatter_kernel(const int* __restrict__ src,
                                                      const int* __restrict__ dst,
                                                      const float* __restrict__ ew,
                                                      int* __restrict__ cursor,
                                                      int* __restrict__ csr_src,
                                                      float* __restrict__ csr_w, int E_) {
    int e = blockIdx.x * 256 + threadIdx.x;
    if (e >= E_) return;
    int d = dst[e];
    int p = atomicAdd(&cursor[d], 1);
    csr_src[p] = src[e];
    csr_w[p]   = ew[e];
}

// ---- per-node aggregation: Out[n] = H[n] + sum_{e in(n)} w_e * H[src_e] ----
// One wave per node; lanes cooperatively load (src,w) pairs, broadcast by shfl,
// so per-edge gathers are independent and pipeline under vmcnt.
__global__ __launch_bounds__(256) void aggregate_kernel(const float* __restrict__ H,
                                                        const int* __restrict__ rp,
                                                        const int* __restrict__ csr_src,
                                                        const float* __restrict__ csr_w,
                                                        float* __restrict__ Out, int n) {
    int node = blockIdx.x * 4 + (threadIdx.x >> 6);
    int lane = threadIdx.x & 63;
    if (node >= n) return;
    const float2* H2 = (const float2*)H;
    float2 acc = H2[(size_t)node * 64 + lane];
    const int e0 = rp[node], e1 = rp[node + 1];
    for (int base = e0; base < e1; base += 64) {
        int cnt = min(64, e1 - base);
        int   sv = 0;
        float wv = 0.f;
        if (base + lane < e1) {
            sv = csr_src[base + lane];
            wv = csr_w[base + lane];
        }
        for (int j = 0; j < cnt; j++) {
            int   sj = __shfl(sv, j);
            float wj = __shfl(wv, j);
            float2 v = H2[(size_t)sj * 64 + lane];
            acc.x += wj * v.x;
            acc.y += wj * v.y;
        }
    }
    ((float2*)Out)[(size_t)node * 64 + lane] = acc;
}

// ---- GEMM: Out[N,128] = relu(A[N,128] @ W[128,128] + b) --------------------
// 64-row x 64-col tile, K=128 staged once. 4x4 microtile. #pragma unroll 1
// keeps ~65 live VGPRs, no spill (R2 lesson).
__global__ __launch_bounds__(256) void gemm128_bias_relu(const float* __restrict__ A,
                                                         const float* __restrict__ W,
                                                         const float* __restrict__ bias,
                                                         float* __restrict__ Out, int nrows) {
    __shared__ float Ws[128 * 64];    // [k][c-local]
    __shared__ float As[64 * 132];    // [r][k], +4 pad
    const int tid  = threadIdx.x;
    const int row0 = blockIdx.x * 64;
    const int col0 = blockIdx.y * 64;

    {   // stage W panel: 128x64
        int c4 = (tid & 15) * 4;
        int kr = tid >> 4;
#pragma unroll
        for (int it = 0; it < 8; ++it, kr += 16)
            *(float4*)(&Ws[kr * 64 + c4]) = *(const float4*)(&W[kr * 128 + col0 + c4]);
    }
    {   // stage A tile: 64x128
        int c4 = (tid & 31) * 4;
        int r  = tid >> 5;
#pragma unroll
        for (int it = 0; it < 8; ++it, r += 8) {
            int grow = row0 + r;
            float4 v = {0.f, 0.f, 0.f, 0.f};
            if (grow < nrows) v = *(const float4*)(&A[(size_t)grow * 128 + c4]);
            *(float4*)(&As[r * 132 + c4]) = v;
        }
    }
    __syncthreads();

    const int rb = (tid >> 4) * 4, cb = (tid & 15) * 4;
    float acc[4][4];
#pragma unroll
    for (int i = 0; i < 4; i++)
#pragma unroll
        for (int j = 0; j < 4; j++) acc[i][j] = 0.f;

#pragma unroll 1
    for (int k = 0; k < 128; k += 4) {
        float4 a0 = *(const float4*)(&As[(rb + 0) * 132 + k]);
        float4 a1 = *(const float4*)(&As[(rb + 1) * 132 + k]);
        float4 a2 = *(const float4*)(&As[(rb + 2) * 132 + k]);
        float4 a3 = *(const float4*)(&As[(rb + 3) * 132 + k]);
        float4 w0 = *(const float4*)(&Ws[(k + 0) * 64 + cb]);
        float4 w1 = *(const float4*)(&Ws[(k + 1) * 64 + cb]);
        float4 w2 = *(const float4*)(&Ws[(k + 2) * 64 + cb]);
        float4 w3 = *(const float4*)(&Ws[(k + 3) * 64 + cb]);
#define ACC_ROW(i, av)                                                   \
        acc[i][0] += av.x * w0.x + av.y * w1.x + av.z * w2.x + av.w * w3.x; \
        acc[i][1] += av.x * w0.y + av.y * w1.y + av.z * w2.y + av.w * w3.y; \
        acc[i][2] += av.x * w0.z + av.y * w1.z + av.z * w2.z + av.w * w3.z; \
        acc[i][3] += av.x * w0.w + av.y * w1.w + av.z * w2.w + av.w * w3.w;
        ACC_ROW(0, a0)
        ACC_ROW(1, a1)
        ACC_ROW(2, a2)
        ACC_ROW(3, a3)
#undef ACC_ROW
    }

    float4 bv = *(const float4*)(&bias[col0 + cb]);
#pragma unroll
    for (int i = 0; i < 4; i++) {
        int grow = row0 + rb + i;
        if (grow < nrows) {
            float4 o;
            o.x = fmaxf(acc[i][0] + bv.x, 0.f);
            o.y = fmaxf(acc[i][1] + bv.y, 0.f);
            o.z = fmaxf(acc[i][2] + bv.z, 0.f);
            o.w = fmaxf(acc[i][3] + bv.w, 0.f);
            *(float4*)(&Out[(size_t)grow * 128 + col0 + cb]) = o;
        }
    }
}

// ---- pooling ---------------------------------------------------------------
__global__ __launch_bounds__(256) void graph_count(const int* __restrict__ batch,
                                                   int* __restrict__ cnt, int n) {
    int t  = blockIdx.x * 256 + threadIdx.x;
    int i0 = t * 16;
    if (i0 >= n) return;
    int end = min(i0 + 16, n);
    int g = batch[i0], c = 0;
    for (int i = i0; i < end; i++) {
        int gi = batch[i];
        if (gi != g) { atomicAdd(&cnt[g], c); g = gi; c = 0; }
        c++;
    }
    atomicAdd(&cnt[g], c);
}

// P[g][k] += sum_{n in g} H[n][k]   (batch is sorted -> run-length flush)
__global__ __launch_bounds__(128) void pool_nodes(const float* __restrict__ H,
                                                  const int* __restrict__ batch,
                                                  float* __restrict__ P, int n) {
    int k     = threadIdx.x;
    int start = blockIdx.x * 256;
    int end   = min(start + 256, n);
    float acc = 0.f;
    int gcur  = batch[start];
    for (int i = start; i < end; i++) {
        int g = batch[i];
        if (g != gcur) { atomicAdd(&P[gcur * 128 + k], acc); acc = 0.f; gcur = g; }
        acc += H[(size_t)i * 128 + k];
    }
    atomicAdd(&P[gcur * 128 + k], acc);
}

// out[g][c] = sum_k P[g][k]*W3[k][c] + cnt[g]*b3[c]
__global__ __launch_bounds__(256) void final_kernel(const float* __restrict__ P,
                                                    const float* __restrict__ W3,
                                                    const float* __restrict__ b3,
                                                    const int* __restrict__ cnt,
                                                    float* __restrict__ out, int total) {
    int idx = blockIdx.x * 256 + threadIdx.x;
    if (idx >= total) return;
    int g = idx / 40, c = idx % 40;
    float acc = (float)cnt[g] * b3[c];
    for (int kk = 0; kk < 128; kk++) acc += P[g * 128 + kk] * W3[kk * 40 + c];
    out[idx] = acc;
}

// ---------------------------------------------------------------------------
extern "C" void kernel_launch(void* const* d_in, const int* in_sizes, int n_in,
                              void* d_out, int out_size, void* d_ws, size_t ws_size,
                              hipStream_t stream) {
    const float* x     = (const float*)d_in[0];
    const int*   ei    = (const int*)d_in[1];
    const float* ew    = (const float*)d_in[2];
    const int*   batch = (const int*)d_in[3];
    const float* W1    = (const float*)d_in[4];
    const float* b1    = (const float*)d_in[5];
    const float* W2    = (const float*)d_in[6];
    const float* b2    = (const float*)d_in[7];
    const float* W3    = (const float*)d_in[8];
    const float* b3    = (const float*)d_in[9];
    float*       out   = (float*)d_out;

    const int E_ = in_sizes[2];   // edge_weight length
    const int N_ = in_sizes[3];   // batch length
    const int* srcp = ei;
    const int* dstp = ei + E_;

    char*  w   = (char*)d_ws;
    size_t off = 0;
    auto take = [&](size_t bytes) -> char* {
        char* p = w + off;
        off = (off + bytes + 255) & ~(size_t)255;
        return p;
    };
    float* A       = (float*)take((size_t)N_ * 128 * 4);
    float* B       = (float*)take((size_t)N_ * 128 * 4);
    int*   rp      = (int*)take((size_t)(N_ + 1) * 4);
    int*   cursor  = (int*)take((size_t)N_ * 4);
    int*   csr_src = (int*)take((size_t)E_ * 4);
    float* csr_w   = (float*)take((size_t)E_ * 4);
    float* P       = (float*)take(64 * 128 * 4);
    int*   cnt     = (int*)take(64 * 4);
    int*   bsum    = (int*)take(1024 * 4);
    (void)ws_size; (void)n_in;

    const int nscan = (N_ + SCAN_BPB - 1) / SCAN_BPB;

    // CSR by destination
    hipMemsetAsync(rp, 0, (size_t)(N_ + 1) * 4, stream);
    hist_kernel<<<(E_ + 255) / 256, 256, 0, stream>>>(dstp, rp, E_);
    scan_partials<<<nscan, SCAN_T, 0, stream>>>(rp, bsum, N_);
    scan_blocksums<<<1, 1024, 0, stream>>>(bsum, nscan);
    scan_apply<<<nscan, SCAN_T, 0, stream>>>(rp, cursor, bsum, N_, E_);
    scatter_kernel<<<(E_ + 255) / 256, 256, 0, stream>>>(srcp, dstp, ew, cursor,
                                                         csr_src, csr_w, E_);

    dim3 ggrid((N_ + 63) / 64, 2);
    // layer 1
    aggregate_kernel<<<(N_ + 3) / 4, 256, 0, stream>>>(x, rp, csr_src, csr_w, A, N_);
    gemm128_bias_relu<<<ggrid, 256, 0, stream>>>(A, W1, b1, B, N_);
    // layer 2
    aggregate_kernel<<<(N_ + 3) / 4, 256, 0, stream>>>(B, rp, csr_src, csr_w, A, N_);
    gemm128_bias_relu<<<ggrid, 256, 0, stream>>>(A, W2, b2, B, N_);

    // layer 3 fused with global_add_pool:
    //   out[g] = pool_g(h2 + agg3) @ W3 + cnt[g]*b3
    aggregate_kernel<<<(N_ + 3) / 4, 256, 0, stream>>>(B, rp, csr_src, csr_w, A, N_);
    hipMemsetAsync(P, 0, 64 * 128 * 4, stream);
    hipMemsetAsync(cnt, 0, 64 * 4, stream);
    graph_count<<<((N_ + 15) / 16 + 255) / 256, 256, 0, stream>>>(batch, cnt, N_);
    pool_nodes<<<(N_ + 255) / 256, 128, 0, stream>>>(A, batch, P, N_);
    final_kernel<<<(out_size + 255) / 256, 256, 0, stream>>>(P, W3, b3, cnt, out, out_size);
}

// Round 5
// 672.881 us; speedup vs baseline: 8.7388x; 1.2280x over previous
//
#include <hip/hip_runtime.h>

// ---------------------------------------------------------------------------
// GIN forward, bf16 internal storage (tolerance is ~3235 absolute; bf16 keeps
// absmax O(10)). 3x { agg = h + scatter(w*h[src]) ; h = relu(agg@W+b) },
// layer 3 + global_add_pool fused: out[g] = pool_g(h2+agg3) @ W3 + cnt[g]*b3.
// Aggregation is gather-BW-bound (R4: 404MB FETCH/dispatch) -> bf16 halves it.
// GEMM uses mfma_f32_16x16x32_bf16; A and B packed with the SAME slot->k
// bijection (k-symmetric operand layouts => result exact regardless of HW's
// internal k distribution); C/D mapping is the HW-verified one.
// ---------------------------------------------------------------------------

typedef __attribute__((ext_vector_type(8))) short short8;
typedef __attribute__((ext_vector_type(4))) float f32x4;

__device__ __forceinline__ unsigned short f2bf(float f) {
    unsigned u = __builtin_bit_cast(unsigned, f);
    u += 0x7fff + ((u >> 16) & 1);           // RNE
    return (unsigned short)(u >> 16);
}
__device__ __forceinline__ float bf2f(unsigned short s) {
    unsigned u = (unsigned)s << 16;
    return __builtin_bit_cast(float, u);
}

// ---- CSR build ------------------------------------------------------------
__global__ __launch_bounds__(256) void hist_kernel(const int* __restrict__ dst,
                                                   int* __restrict__ deg, int E_) {
    int e = blockIdx.x * 256 + threadIdx.x;
    if (e < E_) atomicAdd(&deg[dst[e]], 1);
}

#define SCAN_T 256
#define SCAN_V 4
#define SCAN_BPB (SCAN_T * SCAN_V)

__global__ __launch_bounds__(SCAN_T) void scan_partials(const int* __restrict__ deg,
                                                        int* __restrict__ bsum, int n) {
    const int b = blockIdx.x, tid = threadIdx.x;
    const int i0 = b * SCAN_BPB + tid * SCAN_V;
    int s = 0;
    if (i0 + SCAN_V <= n) {
        int4 v = *(const int4*)(&deg[i0]);
        s = v.x + v.y + v.z + v.w;
    } else {
        for (int j = 0; j < SCAN_V; j++) if (i0 + j < n) s += deg[i0 + j];
    }
    __shared__ int sd[SCAN_T];
    sd[tid] = s;
    __syncthreads();
    for (int ofs = 1; ofs < SCAN_T; ofs <<= 1) {
        int t = (tid >= ofs) ? sd[tid - ofs] : 0;
        __syncthreads();
        sd[tid] += t;
        __syncthreads();
    }
    if (tid == SCAN_T - 1) bsum[b] = sd[tid];
}

__global__ __launch_bounds__(1024) void scan_blocksums(int* __restrict__ bsum, int nb) {
    __shared__ int sd[1024];
    const int tid = threadIdx.x;
    int v = (tid < nb) ? bsum[tid] : 0;
    sd[tid] = v;
    __syncthreads();
    for (int ofs = 1; ofs < 1024; ofs <<= 1) {
        int t = (tid >= ofs) ? sd[tid - ofs] : 0;
        __syncthreads();
        sd[tid] += t;
        __syncthreads();
    }
    if (tid < nb) bsum[tid] = sd[tid] - v;   // exclusive
}

__global__ __launch_bounds__(SCAN_T) void scan_apply(int* __restrict__ rp,
                                                     int* __restrict__ cursor,
                                                     const int* __restrict__ bsum,
                                                     int n, int total) {
    const int b = blockIdx.x, tid = threadIdx.x;
    const int i0 = b * SCAN_BPB + tid * SCAN_V;
    int v[SCAN_V];
    int s = 0;
    if (i0 + SCAN_V <= n) {
        int4 t = *(const int4*)(&rp[i0]);
        v[0] = t.x; v[1] = t.y; v[2] = t.z; v[3] = t.w;
        s = v[0] + v[1] + v[2] + v[3];
    } else {
        for (int j = 0; j < SCAN_V; j++) { v[j] = (i0 + j < n) ? rp[i0 + j] : 0; s += v[j]; }
    }
    __shared__ int sd[SCAN_T];
    sd[tid] = s;
    __syncthreads();
    for (int ofs = 1; ofs < SCAN_T; ofs <<= 1) {
        int t = (tid >= ofs) ? sd[tid - ofs] : 0;
        __syncthreads();
        sd[tid] += t;
        __syncthreads();
    }
    int excl = bsum[b] + sd[tid] - s;
    for (int j = 0; j < SCAN_V; j++) {
        if (i0 + j < n) { rp[i0 + j] = excl; cursor[i0 + j] = excl; }
        excl += v[j];
    }
    if (b == 0 && tid == 0) rp[n] = total;
}

// csr payload packed: {src, float_bits(w)} -> one 8B store / load
__global__ __launch_bounds__(256) void scatter_kernel(const int* __restrict__ src,
                                                      const int* __restrict__ dst,
                                                      const float* __restrict__ ew,
                                                      int* __restrict__ cursor,
                                                      int2* __restrict__ csr, int E_) {
    int e = blockIdx.x * 256 + threadIdx.x;
    if (e >= E_) return;
    int d = dst[e];
    int p = atomicAdd(&cursor[d], 1);
    int2 pr;
    pr.x = src[e];
    pr.y = __float_as_int(ew[e]);
    csr[p] = pr;
}

// ---- f32 -> bf16 row conversion (for x) -----------------------------------
__global__ __launch_bounds__(256) void convert_bf16(const float* __restrict__ in,
                                                    unsigned short* __restrict__ out, int n8) {
    int i = blockIdx.x * 256 + threadIdx.x;
    if (i >= n8) return;
    const float4* in4 = (const float4*)in;
    float4 a = in4[(size_t)i * 2], b = in4[(size_t)i * 2 + 1];
    short8 o;
    o[0] = (short)f2bf(a.x); o[1] = (short)f2bf(a.y);
    o[2] = (short)f2bf(a.z); o[3] = (short)f2bf(a.w);
    o[4] = (short)f2bf(b.x); o[5] = (short)f2bf(b.y);
    o[6] = (short)f2bf(b.z); o[7] = (short)f2bf(b.w);
    ((short8*)out)[i] = o;
}

// ---- W pack: f32 [128][128] -> bf16 fragment order [cf][kg][lane][8] ------
// elem j of (cf,kg,lane): k = kg*32 + (lane>>4)*8 + j, c = cf*16 + (lane&15)
__global__ __launch_bounds__(256) void pack_w(const float* __restrict__ W,
                                              unsigned short* __restrict__ Wp) {
    int idx = blockIdx.x * 256 + threadIdx.x;        // 0..16383
    int j = idx & 7, lane = (idx >> 3) & 63, kg = (idx >> 9) & 3, cf = idx >> 11;
    int k = kg * 32 + ((lane >> 4) & 3) * 8 + j;
    int c = cf * 16 + (lane & 15);
    Wp[idx] = f2bf(W[k * 128 + c]);
}

// ---- aggregation (bf16 rows): Out[n] = H[n] + sum w_e * H[src_e] ----------
// one wave/node; lane owns 2 features (one uint); f32 accumulate.
__global__ __launch_bounds__(256) void aggregate_bf16(const unsigned short* __restrict__ H,
                                                      const int* __restrict__ rp,
                                                      const int2* __restrict__ csr,
                                                      unsigned short* __restrict__ Out, int n) {
    int node = blockIdx.x * 4 + (threadIdx.x >> 6);
    int lane = threadIdx.x & 63;
    if (node >= n) return;
    const unsigned* H32 = (const unsigned*)H;
    unsigned self = H32[(size_t)node * 64 + lane];
    float accx = bf2f((unsigned short)self);
    float accy = bf2f((unsigned short)(self >> 16));
    const int e0 = rp[node], e1 = rp[node + 1];
    for (int base = e0; base < e1; base += 64) {
        int cnt = min(64, e1 - base);
        int   sv = 0;
        float wv = 0.f;
        if (base + lane < e1) {
            int2 p = csr[base + lane];
            sv = p.x;
            wv = __int_as_float(p.y);
        }
        for (int j = 0; j < cnt; j++) {
            int   sj = __shfl(sv, j);
            float wj = __shfl(wv, j);
            unsigned v = H32[(size_t)sj * 64 + lane];
            accx += wj * bf2f((unsigned short)v);
            accy += wj * bf2f((unsigned short)(v >> 16));
        }
    }
    unsigned o = (unsigned)f2bf(accx) | ((unsigned)f2bf(accy) << 16);
    ((unsigned*)Out)[(size_t)node * 64 + lane] = o;
}

// ---- MFMA GEMM: Out[N,128] = relu(A[N,128] @ W + b), bf16 in/out ----------
// 4 waves/block, wave = 16 rows. A frags straight from global (16B/lane).
__global__ __launch_bounds__(256) void gemm_mfma_bias_relu(const unsigned short* __restrict__ A,
                                                           const unsigned short* __restrict__ Wp,
                                                           const float* __restrict__ bias,
                                                           unsigned short* __restrict__ Out,
                                                           int nrows) {
    const int wave = threadIdx.x >> 6;
    const int lane = threadIdx.x & 63;
    const int rbase = blockIdx.x * 64 + wave * 16;
    const int arow = rbase + (lane & 15);
    const int arow_c = min(arow, nrows - 1);

    const short8* Arow = (const short8*)(A + (size_t)arow_c * 128);
    short8 a[4];
#pragma unroll
    for (int kg = 0; kg < 4; kg++) a[kg] = Arow[kg * 4 + (lane >> 4)];

    const short8* Bp = (const short8*)Wp;
    const int drow = rbase + ((lane >> 4) << 2);
    const int dcol = lane & 15;
#pragma unroll
    for (int cf = 0; cf < 8; cf++) {
        f32x4 acc = {0.f, 0.f, 0.f, 0.f};
#pragma unroll
        for (int kg = 0; kg < 4; kg++) {
            short8 b = Bp[(cf * 4 + kg) * 64 + lane];
            acc = __builtin_amdgcn_mfma_f32_16x16x32_bf16(a[kg], b, acc, 0, 0, 0);
        }
        float bv = bias[cf * 16 + dcol];
#pragma unroll
        for (int i = 0; i < 4; i++) {
            int r = drow + i;
            if (r < nrows) {
                float v = fmaxf(acc[i] + bv, 0.f);
                Out[(size_t)r * 128 + cf * 16 + dcol] = f2bf(v);
            }
        }
    }
}

// ---- pooling ---------------------------------------------------------------
__global__ __launch_bounds__(256) void graph_count(const int* __restrict__ batch,
                                                   int* __restrict__ cnt, int n) {
    int t  = blockIdx.x * 256 + threadIdx.x;
    int i0 = t * 16;
    if (i0 >= n) return;
    int end = min(i0 + 16, n);
    int g = batch[i0], c = 0;
    for (int i = i0; i < end; i++) {
        int gi = batch[i];
        if (gi != g) { atomicAdd(&cnt[g], c); g = gi; c = 0; }
        c++;
    }
    atomicAdd(&cnt[g], c);
}

// P[g][k] += sum_{n in g} H[n][k]  (bf16 rows, sorted batch run-length flush)
__global__ __launch_bounds__(128) void pool_nodes(const unsigned short* __restrict__ H,
                                                  const int* __restrict__ batch,
                                                  float* __restrict__ P, int n) {
    int k     = threadIdx.x;
    int start = blockIdx.x * 256;
    int end   = min(start + 256, n);
    float acc = 0.f;
    int gcur  = batch[start];
    for (int i = start; i < end; i++) {
        int g = batch[i];
        if (g != gcur) { atomicAdd(&P[gcur * 128 + k], acc); acc = 0.f; gcur = g; }
        acc += bf2f(H[(size_t)i * 128 + k]);
    }
    atomicAdd(&P[gcur * 128 + k], acc);
}

// out[g][c] = sum_k P[g][k]*W3[k][c] + cnt[g]*b3[c]
__global__ __launch_bounds__(256) void final_kernel(const float* __restrict__ P,
                                                    const float* __restrict__ W3,
                                                    const float* __restrict__ b3,
                                                    const int* __restrict__ cnt,
                                                    float* __restrict__ out, int total) {
    int idx = blockIdx.x * 256 + threadIdx.x;
    if (idx >= total) return;
    int g = idx / 40, c = idx % 40;
    float acc = (float)cnt[g] * b3[c];
    for (int kk = 0; kk < 128; kk++) acc += P[g * 128 + kk] * W3[kk * 40 + c];
    out[idx] = acc;
}

// ---------------------------------------------------------------------------
extern "C" void kernel_launch(void* const* d_in, const int* in_sizes, int n_in,
                              void* d_out, int out_size, void* d_ws, size_t ws_size,
                              hipStream_t stream) {
    const float* x     = (const float*)d_in[0];
    const int*   ei    = (const int*)d_in[1];
    const float* ew    = (const float*)d_in[2];
    const int*   batch = (const int*)d_in[3];
    const float* W1    = (const float*)d_in[4];
    const float* b1    = (const float*)d_in[5];
    const float* W2    = (const float*)d_in[6];
    const float* b2    = (const float*)d_in[7];
    const float* W3    = (const float*)d_in[8];
    const float* b3    = (const float*)d_in[9];
    float*       out   = (float*)d_out;

    const int E_ = in_sizes[2];   // edge_weight length
    const int N_ = in_sizes[3];   // batch length
    const int* srcp = ei;
    const int* dstp = ei + E_;

    char*  w   = (char*)d_ws;
    size_t off = 0;
    auto take = [&](size_t bytes) -> char* {
        char* p = w + off;
        off = (off + bytes + 255) & ~(size_t)255;
        return p;
    };
    unsigned short* xb  = (unsigned short*)take((size_t)N_ * 128 * 2);
    unsigned short* Ha  = (unsigned short*)take((size_t)N_ * 128 * 2);  // agg output
    unsigned short* Hb  = (unsigned short*)take((size_t)N_ * 128 * 2);  // gemm output
    int*   rp      = (int*)take((size_t)(N_ + 1) * 4);
    int*   cursor  = (int*)take((size_t)N_ * 4);
    int2*  csr     = (int2*)take((size_t)E_ * 8);
    float* P       = (float*)take(64 * 128 * 4);
    int*   cnt     = (int*)take(64 * 4);
    int*   bsum    = (int*)take(1024 * 4);
    unsigned short* W1p = (unsigned short*)take(16384 * 2);
    unsigned short* W2p = (unsigned short*)take(16384 * 2);
    (void)ws_size; (void)n_in;

    const int nscan = (N_ + SCAN_BPB - 1) / SCAN_BPB;

    // CSR by destination
    hipMemsetAsync(rp, 0, (size_t)(N_ + 1) * 4, stream);
    hist_kernel<<<(E_ + 255) / 256, 256, 0, stream>>>(dstp, rp, E_);
    scan_partials<<<nscan, SCAN_T, 0, stream>>>(rp, bsum, N_);
    scan_blocksums<<<1, 1024, 0, stream>>>(bsum, nscan);
    scan_apply<<<nscan, SCAN_T, 0, stream>>>(rp, cursor, bsum, N_, E_);
    scatter_kernel<<<(E_ + 255) / 256, 256, 0, stream>>>(srcp, dstp, ew, cursor, csr, E_);

    // bf16 conversions / weight packing
    convert_bf16<<<(N_ * 16 + 255) / 256, 256, 0, stream>>>(x, xb, N_ * 16);  // N*128/8
    pack_w<<<64, 256, 0, stream>>>(W1, W1p);
    pack_w<<<64, 256, 0, stream>>>(W2, W2p);

    const int agrid = (N_ + 3) / 4;
    const int ggrid = (N_ + 63) / 64;
    // layer 1
    aggregate_bf16<<<agrid, 256, 0, stream>>>(xb, rp, csr, Ha, N_);
    gemm_mfma_bias_relu<<<ggrid, 256, 0, stream>>>(Ha, W1p, b1, Hb, N_);
    // layer 2
    aggregate_bf16<<<agrid, 256, 0, stream>>>(Hb, rp, csr, Ha, N_);
    gemm_mfma_bias_relu<<<ggrid, 256, 0, stream>>>(Ha, W2p, b2, Hb, N_);
    // layer 3 aggregate (h2 + agg3), then pooled path
    aggregate_bf16<<<agrid, 256, 0, stream>>>(Hb, rp, csr, Ha, N_);

    hipMemsetAsync(P, 0, 64 * 128 * 4, stream);
    hipMemsetAsync(cnt, 0, 64 * 4, stream);
    graph_count<<<((N_ + 15) / 16 + 255) / 256, 256, 0, stream>>>(batch, cnt, N_);
    pool_nodes<<<(N_ + 255) / 256, 128, 0, stream>>>(Ha, batch, P, N_);
    final_kernel<<<(out_size + 255) / 256, 256, 0, stream>>>(P, W3, b3, cnt, out, out_size);
}

// Round 6
// 542.359 us; speedup vs baseline: 10.8418x; 1.2407x over previous
//
#include <hip/hip_runtime.h>

// ---------------------------------------------------------------------------
// GIN forward, bf16 internal storage. 3x { agg = h + scatter(w*h[src]);
// h = relu(agg@W+b) }, layer3+pool fused: out[g]=pool_g(h2+agg3)@W3+cnt*b3.
// R5 lesson: random 8B CSR scatter writes cost a full 64B line each
// (WRITE_SIZE 100MB = 1.6M x 64B, no cross-XCD write merging). This round
// rebuilds CSR via bucketed counting sort: ALL global writes coalesced.
//   bucket = dst>>8 (256 nodes/bucket); payload packs (src:17 | dstlo:8, w).
// ---------------------------------------------------------------------------

typedef __attribute__((ext_vector_type(8))) short short8;
typedef __attribute__((ext_vector_type(4))) float f32x4;

__device__ __forceinline__ unsigned short f2bf(float f) {
    unsigned u = __builtin_bit_cast(unsigned, f);
    u += 0x7fff + ((u >> 16) & 1);           // RNE
    return (unsigned short)(u >> 16);
}
__device__ __forceinline__ float bf2f(unsigned short s) {
    unsigned u = (unsigned)s << 16;
    return __builtin_bit_cast(float, u);
}

#define BKT_SHIFT 8
#define BKT_NODES 256            // nodes per bucket; NB = ceil(N/256) <= 512 (N < 131072)
#define PCHUNK 4096              // edges per partition block
#define SB_CAP 7168              // max edges per bucket in sort LDS (mean 4096, 34+ sigma)

// ---- bucket-level histogram (LDS-aggregated, coalesced reads) -------------
__global__ __launch_bounds__(256) void bucket_hist(const int* __restrict__ dst,
                                                   int* __restrict__ bh, int E_) {
    __shared__ int lh[512];
    for (int i = threadIdx.x; i < 512; i += 256) lh[i] = 0;
    __syncthreads();
    for (int i = blockIdx.x * 256 + threadIdx.x; i < E_; i += gridDim.x * 256)
        atomicAdd(&lh[dst[i] >> BKT_SHIFT], 1);
    __syncthreads();
    for (int i = threadIdx.x; i < 512; i += 256)
        if (lh[i]) atomicAdd(&bh[i], lh[i]);
}

// ---- bucket scan: bstart (exclusive), gcursor init, rp[N]=E ---------------
__global__ __launch_bounds__(512) void bucket_scan(const int* __restrict__ bh,
                                                   int* __restrict__ bstart,
                                                   int* __restrict__ gcur,
                                                   int* __restrict__ rp,
                                                   int NB, int N_, int E_) {
    __shared__ int sd[512];
    const int tid = threadIdx.x;
    int v = (tid < NB) ? bh[tid] : 0;
    sd[tid] = v;
    __syncthreads();
    for (int ofs = 1; ofs < 512; ofs <<= 1) {
        int t = (tid >= ofs) ? sd[tid - ofs] : 0;
        __syncthreads();
        sd[tid] += t;
        __syncthreads();
    }
    int excl = sd[tid] - v;
    if (tid < NB) { bstart[tid] = excl; gcur[tid] = excl; }
    if (tid == NB - 1) bstart[NB] = excl + v;   // == E_
    if (tid == 0) rp[N_] = E_;
}

// ---- partition edges into bucket regions (coalesced run writes) -----------
__global__ __launch_bounds__(256) void partition_edges(const int* __restrict__ src,
                                                       const int* __restrict__ dst,
                                                       const float* __restrict__ ew,
                                                       int* __restrict__ gcur,
                                                       uint2* __restrict__ temp, int E_) {
    __shared__ int lcur[512];             // per-bucket local cursor
    __shared__ int lexcl[512];            // per-bucket local exclusive offset
    __shared__ int gbase[512];            // per-bucket reserved global base
    __shared__ unsigned short bof[PCHUNK];
    __shared__ uint2 stag[PCHUNK];
    __shared__ int sd[256];
    const int tid = threadIdx.x;
    const int e0  = blockIdx.x * PCHUNK;
    const int n   = min(PCHUNK, E_ - e0);

    for (int i = tid; i < 512; i += 256) lcur[i] = 0;
    __syncthreads();
    for (int i = tid; i < n; i += 256)
        atomicAdd(&lcur[dst[e0 + i] >> BKT_SHIFT], 1);
    __syncthreads();
    // scan 512 counters: pair-sum -> 256-thread Hillis-Steele -> expand
    const int a0 = lcur[2 * tid], a1 = lcur[2 * tid + 1];
    const int ps = a0 + a1;
    sd[tid] = ps;
    __syncthreads();
    for (int ofs = 1; ofs < 256; ofs <<= 1) {
        int t = (tid >= ofs) ? sd[tid - ofs] : 0;
        __syncthreads();
        sd[tid] += t;
        __syncthreads();
    }
    const int pexcl = sd[tid] - ps;
    __syncthreads();
    lexcl[2 * tid] = pexcl;      lexcl[2 * tid + 1] = pexcl + a0;
    lcur [2 * tid] = pexcl;      lcur [2 * tid + 1] = pexcl + a0;
    __syncthreads();
    // place into LDS staging, bucket-grouped
    for (int i = tid; i < n; i += 256) {
        int   s = src[e0 + i], d = dst[e0 + i];
        float wv = ew[e0 + i];
        int b = d >> BKT_SHIFT;
        int p = atomicAdd(&lcur[b], 1);
        stag[p].x = (unsigned)s | ((unsigned)(d & (BKT_NODES - 1)) << 17);
        stag[p].y = __float_as_uint(wv);
        bof[p] = (unsigned short)b;
    }
    __syncthreads();
    // reserve global runs (1 atomic per non-empty bucket)
    if (a0) gbase[2 * tid]     = atomicAdd(&gcur[2 * tid],     a0);
    if (a1) gbase[2 * tid + 1] = atomicAdd(&gcur[2 * tid + 1], a1);
    __syncthreads();
    // copy runs out: consecutive i in a bucket -> consecutive global addresses
    for (int i = tid; i < n; i += 256) {
        int b = bof[i];
        temp[gbase[b] + (i - lexcl[b])] = stag[i];
    }
}

// ---- per-bucket counting sort by dst low bits; writes csr + rp ------------
__global__ __launch_bounds__(256) void sort_bucket(const uint2* __restrict__ temp,
                                                   const int* __restrict__ bstart,
                                                   uint2* __restrict__ csr,
                                                   int* __restrict__ rp, int N_) {
    __shared__ int h[256], hcur[256], sd[256];
    __shared__ uint2 outb[SB_CAP];
    const int b = blockIdx.x, tid = threadIdx.x;
    const int lo = bstart[b], hi = bstart[b + 1];
    const int L = hi - lo;
    h[tid] = 0;
    __syncthreads();
    for (int i = tid; i < L; i += 256)
        atomicAdd(&h[(temp[lo + i].x >> 17) & (BKT_NODES - 1)], 1);
    __syncthreads();
    int v = h[tid];
    sd[tid] = v;
    __syncthreads();
    for (int ofs = 1; ofs < 256; ofs <<= 1) {
        int t = (tid >= ofs) ? sd[tid - ofs] : 0;
        __syncthreads();
        sd[tid] += t;
        __syncthreads();
    }
    const int excl = sd[tid] - v;
    hcur[tid] = excl;
    const int node = b * BKT_NODES + tid;
    if (node <= N_) rp[node] = lo + excl;     // row pointers, coalesced
    __syncthreads();
    for (int i = tid; i < L; i += 256) {
        uint2 p = temp[lo + i];
        int pos = atomicAdd(&hcur[(p.x >> 17) & (BKT_NODES - 1)], 1);
        outb[pos] = p;
    }
    __syncthreads();
    for (int i = tid; i < L; i += 256) csr[lo + i] = outb[i];   // coalesced
}

// ---- f32 -> bf16 row conversion (for x) -----------------------------------
__global__ __launch_bounds__(256) void convert_bf16(const float* __restrict__ in,
                                                    unsigned short* __restrict__ out, int n8) {
    int i = blockIdx.x * 256 + threadIdx.x;
    if (i >= n8) return;
    const float4* in4 = (const float4*)in;
    float4 a = in4[(size_t)i * 2], b = in4[(size_t)i * 2 + 1];
    short8 o;
    o[0] = (short)f2bf(a.x); o[1] = (short)f2bf(a.y);
    o[2] = (short)f2bf(a.z); o[3] = (short)f2bf(a.w);
    o[4] = (short)f2bf(b.x); o[5] = (short)f2bf(b.y);
    o[6] = (short)f2bf(b.z); o[7] = (short)f2bf(b.w);
    ((short8*)out)[i] = o;
}

// ---- W pack: f32 [128][128] -> bf16 fragment order [cf][kg][lane][8] ------
__global__ __launch_bounds__(256) void pack_w(const float* __restrict__ W,
                                              unsigned short* __restrict__ Wp) {
    int idx = blockIdx.x * 256 + threadIdx.x;        // 0..16383
    int j = idx & 7, lane = (idx >> 3) & 63, kg = (idx >> 9) & 3, cf = idx >> 11;
    int k = kg * 32 + ((lane >> 4) & 3) * 8 + j;
    int c = cf * 16 + (lane & 15);
    Wp[idx] = f2bf(W[k * 128 + c]);
}

// ---- aggregation (bf16 rows): Out[n] = H[n] + sum w_e * H[src_e] ----------
__global__ __launch_bounds__(256) void aggregate_bf16(const unsigned short* __restrict__ H,
                                                      const int* __restrict__ rp,
                                                      const int2* __restrict__ csr,
                                                      unsigned short* __restrict__ Out, int n) {
    int node = blockIdx.x * 4 + (threadIdx.x >> 6);
    int lane = threadIdx.x & 63;
    if (node >= n) return;
    const unsigned* H32 = (const unsigned*)H;
    unsigned self = H32[(size_t)node * 64 + lane];
    float accx = bf2f((unsigned short)self);
    float accy = bf2f((unsigned short)(self >> 16));
    const int e0 = rp[node], e1 = rp[node + 1];
    for (int base = e0; base < e1; base += 64) {
        int cnt = min(64, e1 - base);
        int   sv = 0;
        float wv = 0.f;
        if (base + lane < e1) {
            int2 p = csr[base + lane];
            sv = p.x & 0x1FFFF;
            wv = __int_as_float(p.y);
        }
        for (int j = 0; j < cnt; j++) {
            int   sj = __shfl(sv, j);
            float wj = __shfl(wv, j);
            unsigned v = H32[(size_t)sj * 64 + lane];
            accx += wj * bf2f((unsigned short)v);
            accy += wj * bf2f((unsigned short)(v >> 16));
        }
    }
    unsigned o = (unsigned)f2bf(accx) | ((unsigned)f2bf(accy) << 16);
    ((unsigned*)Out)[(size_t)node * 64 + lane] = o;
}

// ---- MFMA GEMM: Out[N,128] = relu(A[N,128] @ W + b), bf16 in/out ----------
__global__ __launch_bounds__(256) void gemm_mfma_bias_relu(const unsigned short* __restrict__ A,
                                                           const unsigned short* __restrict__ Wp,
                                                           const float* __restrict__ bias,
                                                           unsigned short* __restrict__ Out,
                                                           int nrows) {
    const int wave = threadIdx.x >> 6;
    const int lane = threadIdx.x & 63;
    const int rbase = blockIdx.x * 64 + wave * 16;
    const int arow = rbase + (lane & 15);
    const int arow_c = min(arow, nrows - 1);

    const short8* Arow = (const short8*)(A + (size_t)arow_c * 128);
    short8 a[4];
#pragma unroll
    for (int kg = 0; kg < 4; kg++) a[kg] = Arow[kg * 4 + (lane >> 4)];

    const short8* Bp = (const short8*)Wp;
    const int drow = rbase + ((lane >> 4) << 2);
    const int dcol = lane & 15;
#pragma unroll
    for (int cf = 0; cf < 8; cf++) {
        f32x4 acc = {0.f, 0.f, 0.f, 0.f};
#pragma unroll
        for (int kg = 0; kg < 4; kg++) {
            short8 b = Bp[(cf * 4 + kg) * 64 + lane];
            acc = __builtin_amdgcn_mfma_f32_16x16x32_bf16(a[kg], b, acc, 0, 0, 0);
        }
        float bv = bias[cf * 16 + dcol];
#pragma unroll
        for (int i = 0; i < 4; i++) {
            int r = drow + i;
            if (r < nrows) {
                float v = fmaxf(acc[i] + bv, 0.f);
                Out[(size_t)r * 128 + cf * 16 + dcol] = f2bf(v);
            }
        }
    }
}

// ---- pooling ---------------------------------------------------------------
__global__ __launch_bounds__(256) void graph_count(const int* __restrict__ batch,
                                                   int* __restrict__ cnt, int n) {
    int t  = blockIdx.x * 256 + threadIdx.x;
    int i0 = t * 16;
    if (i0 >= n) return;
    int end = min(i0 + 16, n);
    int g = batch[i0], c = 0;
    for (int i = i0; i < end; i++) {
        int gi = batch[i];
        if (gi != g) { atomicAdd(&cnt[g], c); g = gi; c = 0; }
        c++;
    }
    atomicAdd(&cnt[g], c);
}

__global__ __launch_bounds__(128) void pool_nodes(const unsigned short* __restrict__ H,
                                                  const int* __restrict__ batch,
                                                  float* __restrict__ P, int n) {
    int k     = threadIdx.x;
    int start = blockIdx.x * 256;
    int end   = min(start + 256, n);
    float acc = 0.f;
    int gcur  = batch[start];
    for (int i = start; i < end; i++) {
        int g = batch[i];
        if (g != gcur) { atomicAdd(&P[gcur * 128 + k], acc); acc = 0.f; gcur = g; }
        acc += bf2f(H[(size_t)i * 128 + k]);
    }
    atomicAdd(&P[gcur * 128 + k], acc);
}

__global__ __launch_bounds__(256) void final_kernel(const float* __restrict__ P,
                                                    const float* __restrict__ W3,
                                                    const float* __restrict__ b3,
                                                    const int* __restrict__ cnt,
                                                    float* __restrict__ out, int total) {
    int idx = blockIdx.x * 256 + threadIdx.x;
    if (idx >= total) return;
    int g = idx / 40, c = idx % 40;
    float acc = (float)cnt[g] * b3[c];
    for (int kk = 0; kk < 128; kk++) acc += P[g * 128 + kk] * W3[kk * 40 + c];
    out[idx] = acc;
}

// ---------------------------------------------------------------------------
extern "C" void kernel_launch(void* const* d_in, const int* in_sizes, int n_in,
                              void* d_out, int out_size, void* d_ws, size_t ws_size,
                              hipStream_t stream) {
    const float* x     = (const float*)d_in[0];
    const int*   ei    = (const int*)d_in[1];
    const float* ew    = (const float*)d_in[2];
    const int*   batch = (const int*)d_in[3];
    const float* W1    = (const float*)d_in[4];
    const float* b1    = (const float*)d_in[5];
    const float* W2    = (const float*)d_in[6];
    const float* b2    = (const float*)d_in[7];
    const float* W3    = (const float*)d_in[8];
    const float* b3    = (const float*)d_in[9];
    float*       out   = (float*)d_out;

    const int E_ = in_sizes[2];   // edge_weight length
    const int N_ = in_sizes[3];   // batch length  (N_ < 131072 for 17-bit src pack)
    const int* srcp = ei;
    const int* dstp = ei + E_;
    const int NB = (N_ + BKT_NODES - 1) >> BKT_SHIFT;

    char*  w   = (char*)d_ws;
    size_t off = 0;
    auto take = [&](size_t bytes) -> char* {
        char* p = w + off;
        off = (off + bytes + 255) & ~(size_t)255;
        return p;
    };
    unsigned short* xb  = (unsigned short*)take((size_t)N_ * 128 * 2);
    unsigned short* Ha  = (unsigned short*)take((size_t)N_ * 128 * 2);
    unsigned short* Hb  = (unsigned short*)take((size_t)N_ * 128 * 2);
    int*   rp      = (int*)take((size_t)(N_ + 1) * 4);
    uint2* tempE   = (uint2*)take((size_t)E_ * 8);
    uint2* csr     = (uint2*)take((size_t)E_ * 8);
    int*   bh      = (int*)take(512 * 4);
    int*   bstart  = (int*)take(513 * 4);
    int*   gcur    = (int*)take(512 * 4);
    float* P       = (float*)take(64 * 128 * 4);
    int*   cnt     = (int*)take(64 * 4);
    unsigned short* W1p = (unsigned short*)take(16384 * 2);
    unsigned short* W2p = (unsigned short*)take(16384 * 2);
    (void)ws_size; (void)n_in;

    // ---- CSR build via bucketed counting sort (all writes coalesced) ----
    hipMemsetAsync(bh, 0, 512 * 4, stream);
    bucket_hist<<<1024, 256, 0, stream>>>(dstp, bh, E_);
    bucket_scan<<<1, 512, 0, stream>>>(bh, bstart, gcur, rp, NB, N_, E_);
    partition_edges<<<(E_ + PCHUNK - 1) / PCHUNK, 256, 0, stream>>>(srcp, dstp, ew,
                                                                    gcur, tempE, E_);
    sort_bucket<<<NB, 256, 0, stream>>>(tempE, bstart, csr, rp, N_);

    // bf16 conversions / weight packing
    convert_bf16<<<(N_ * 16 + 255) / 256, 256, 0, stream>>>(x, xb, N_ * 16);
    pack_w<<<64, 256, 0, stream>>>(W1, W1p);
    pack_w<<<64, 256, 0, stream>>>(W2, W2p);

    const int agrid = (N_ + 3) / 4;
    const int ggrid = (N_ + 63) / 64;
    // layer 1
    aggregate_bf16<<<agrid, 256, 0, stream>>>(xb, rp, (const int2*)csr, Ha, N_);
    gemm_mfma_bias_relu<<<ggrid, 256, 0, stream>>>(Ha, W1p, b1, Hb, N_);
    // layer 2
    aggregate_bf16<<<agrid, 256, 0, stream>>>(Hb, rp, (const int2*)csr, Ha, N_);
    gemm_mfma_bias_relu<<<ggrid, 256, 0, stream>>>(Ha, W2p, b2, Hb, N_);
    // layer 3 aggregate (h2 + agg3), then pooled path
    aggregate_bf16<<<agrid, 256, 0, stream>>>(Hb, rp, (const int2*)csr, Ha, N_);

    hipMemsetAsync(P, 0, 64 * 128 * 4, stream);
    hipMemsetAsync(cnt, 0, 64 * 4, stream);
    graph_count<<<((N_ + 15) / 16 + 255) / 256, 256, 0, stream>>>(batch, cnt, N_);
    pool_nodes<<<(N_ + 255) / 256, 128, 0, stream>>>(Ha, batch, P, N_);
    final_kernel<<<(out_size + 255) / 256, 256, 0, stream>>>(P, W3, b3, cnt, out, out_size);
}

// Round 7
// 421.660 us; speedup vs baseline: 13.9453x; 1.2862x over previous
//
#include <hip/hip_runtime.h>

// ---------------------------------------------------------------------------
// GIN forward, bf16 internal storage. 3x { agg = h + scatter(w*h[src]);
// h = relu(agg@W+b) }, layer3+pool fused: out[g]=pool_g(h2+agg3)@W3+cnt*b3.
// CSR built by bucketed counting sort (R5: coalesced writes only).
// R6 lesson: aggregate was load-issue-bound (2.1TB/s @ 28% VALU, 71% occ).
// Now: 4 edges in parallel per wave (16 lanes x uint4 each => 1KB/instr),
// shfl_xor cross-group reduce, shift/mask bf16 unpack. ~5 VALU/edge.
// ---------------------------------------------------------------------------

typedef __attribute__((ext_vector_type(8))) short short8;
typedef __attribute__((ext_vector_type(4))) float f32x4;

__device__ __forceinline__ unsigned short f2bf(float f) {
    unsigned u = __builtin_bit_cast(unsigned, f);
    u += 0x7fff + ((u >> 16) & 1);           // RNE
    return (unsigned short)(u >> 16);
}
__device__ __forceinline__ float bf2f(unsigned short s) {
    unsigned u = (unsigned)s << 16;
    return __builtin_bit_cast(float, u);
}
__device__ __forceinline__ float bflo(unsigned u) {
    return __builtin_bit_cast(float, u << 16);
}
__device__ __forceinline__ float bfhi(unsigned u) {
    return __builtin_bit_cast(float, u & 0xffff0000u);
}
__device__ __forceinline__ unsigned packbf(float a, float b) {
    return (unsigned)f2bf(a) | ((unsigned)f2bf(b) << 16);
}

#define BKT_SHIFT 8
#define BKT_NODES 256            // nodes per bucket; NB <= 512 (N < 131072)
#define PCHUNK 4096              // edges per partition block
#define SB_CAP 7168              // max edges per bucket in sort LDS

// ---- bucket-level histogram (LDS-aggregated, coalesced reads) -------------
__global__ __launch_bounds__(256) void bucket_hist(const int* __restrict__ dst,
                                                   int* __restrict__ bh, int E_) {
    __shared__ int lh[512];
    for (int i = threadIdx.x; i < 512; i += 256) lh[i] = 0;
    __syncthreads();
    for (int i = blockIdx.x * 256 + threadIdx.x; i < E_; i += gridDim.x * 256)
        atomicAdd(&lh[dst[i] >> BKT_SHIFT], 1);
    __syncthreads();
    for (int i = threadIdx.x; i < 512; i += 256)
        if (lh[i]) atomicAdd(&bh[i], lh[i]);
}

// ---- bucket scan: bstart (exclusive), gcursor init, rp[N]=E ---------------
__global__ __launch_bounds__(512) void bucket_scan(const int* __restrict__ bh,
                                                   int* __restrict__ bstart,
                                                   int* __restrict__ gcur,
                                                   int* __restrict__ rp,
                                                   int NB, int N_, int E_) {
    __shared__ int sd[512];
    const int tid = threadIdx.x;
    int v = (tid < NB) ? bh[tid] : 0;
    sd[tid] = v;
    __syncthreads();
    for (int ofs = 1; ofs < 512; ofs <<= 1) {
        int t = (tid >= ofs) ? sd[tid - ofs] : 0;
        __syncthreads();
        sd[tid] += t;
        __syncthreads();
    }
    int excl = sd[tid] - v;
    if (tid < NB) { bstart[tid] = excl; gcur[tid] = excl; }
    if (tid == NB - 1) bstart[NB] = excl + v;   // == E_
    if (tid == 0) rp[N_] = E_;
}

// ---- partition edges into bucket regions (coalesced run writes) -----------
__global__ __launch_bounds__(256) void partition_edges(const int* __restrict__ src,
                                                       const int* __restrict__ dst,
                                                       const float* __restrict__ ew,
                                                       int* __restrict__ gcur,
                                                       uint2* __restrict__ temp, int E_) {
    __shared__ int lcur[512];
    __shared__ int lexcl[512];
    __shared__ int gbase[512];
    __shared__ unsigned short bof[PCHUNK];
    __shared__ uint2 stag[PCHUNK];
    __shared__ int sd[256];
    const int tid = threadIdx.x;
    const int e0  = blockIdx.x * PCHUNK;
    const int n   = min(PCHUNK, E_ - e0);

    for (int i = tid; i < 512; i += 256) lcur[i] = 0;
    __syncthreads();
    for (int i = tid; i < n; i += 256)
        atomicAdd(&lcur[dst[e0 + i] >> BKT_SHIFT], 1);
    __syncthreads();
    const int a0 = lcur[2 * tid], a1 = lcur[2 * tid + 1];
    const int ps = a0 + a1;
    sd[tid] = ps;
    __syncthreads();
    for (int ofs = 1; ofs < 256; ofs <<= 1) {
        int t = (tid >= ofs) ? sd[tid - ofs] : 0;
        __syncthreads();
        sd[tid] += t;
        __syncthreads();
    }
    const int pexcl = sd[tid] - ps;
    __syncthreads();
    lexcl[2 * tid] = pexcl;      lexcl[2 * tid + 1] = pexcl + a0;
    lcur [2 * tid] = pexcl;      lcur [2 * tid + 1] = pexcl + a0;
    __syncthreads();
    for (int i = tid; i < n; i += 256) {
        int   s = src[e0 + i], d = dst[e0 + i];
        float wv = ew[e0 + i];
        int b = d >> BKT_SHIFT;
        int p = atomicAdd(&lcur[b], 1);
        stag[p].x = (unsigned)s | ((unsigned)(d & (BKT_NODES - 1)) << 17);
        stag[p].y = __float_as_uint(wv);
        bof[p] = (unsigned short)b;
    }
    __syncthreads();
    if (a0) gbase[2 * tid]     = atomicAdd(&gcur[2 * tid],     a0);
    if (a1) gbase[2 * tid + 1] = atomicAdd(&gcur[2 * tid + 1], a1);
    __syncthreads();
    for (int i = tid; i < n; i += 256) {
        int b = bof[i];
        temp[gbase[b] + (i - lexcl[b])] = stag[i];
    }
}

// ---- per-bucket counting sort by dst low bits; writes csr + rp ------------
__global__ __launch_bounds__(256) void sort_bucket(const uint2* __restrict__ temp,
                                                   const int* __restrict__ bstart,
                                                   uint2* __restrict__ csr,
                                                   int* __restrict__ rp, int N_) {
    __shared__ int h[256], hcur[256], sd[256];
    __shared__ uint2 outb[SB_CAP];
    const int b = blockIdx.x, tid = threadIdx.x;
    const int lo = bstart[b], hi = bstart[b + 1];
    const int L = hi - lo;
    h[tid] = 0;
    __syncthreads();
    for (int i = tid; i < L; i += 256)
        atomicAdd(&h[(temp[lo + i].x >> 17) & (BKT_NODES - 1)], 1);
    __syncthreads();
    int v = h[tid];
    sd[tid] = v;
    __syncthreads();
    for (int ofs = 1; ofs < 256; ofs <<= 1) {
        int t = (tid >= ofs) ? sd[tid - ofs] : 0;
        __syncthreads();
        sd[tid] += t;
        __syncthreads();
    }
    const int excl = sd[tid] - v;
    hcur[tid] = excl;
    const int node = b * BKT_NODES + tid;
    if (node <= N_) rp[node] = lo + excl;
    __syncthreads();
    for (int i = tid; i < L; i += 256) {
        uint2 p = temp[lo + i];
        int pos = atomicAdd(&hcur[(p.x >> 17) & (BKT_NODES - 1)], 1);
        outb[pos] = p;
    }
    __syncthreads();
    for (int i = tid; i < L; i += 256) csr[lo + i] = outb[i];
}

// ---- f32 -> bf16 row conversion (for x) -----------------------------------
__global__ __launch_bounds__(256) void convert_bf16(const float* __restrict__ in,
                                                    unsigned short* __restrict__ out, int n8) {
    int i = blockIdx.x * 256 + threadIdx.x;
    if (i >= n8) return;
    const float4* in4 = (const float4*)in;
    float4 a = in4[(size_t)i * 2], b = in4[(size_t)i * 2 + 1];
    short8 o;
    o[0] = (short)f2bf(a.x); o[1] = (short)f2bf(a.y);
    o[2] = (short)f2bf(a.z); o[3] = (short)f2bf(a.w);
    o[4] = (short)f2bf(b.x); o[5] = (short)f2bf(b.y);
    o[6] = (short)f2bf(b.z); o[7] = (short)f2bf(b.w);
    ((short8*)out)[i] = o;
}

// ---- W pack: f32 [128][128] -> bf16 fragment order [cf][kg][lane][8] ------
__global__ __launch_bounds__(256) void pack_w(const float* __restrict__ W,
                                              unsigned short* __restrict__ Wp) {
    int idx = blockIdx.x * 256 + threadIdx.x;        // 0..16383
    int j = idx & 7, lane = (idx >> 3) & 63, kg = (idx >> 9) & 3, cf = idx >> 11;
    int k = kg * 32 + ((lane >> 4) & 3) * 8 + j;
    int c = cf * 16 + (lane & 15);
    Wp[idx] = f2bf(W[k * 128 + c]);
}

// ---- aggregation (bf16 rows): Out[n] = H[n] + sum w_e * H[src_e] ----------
// One wave per node, 4 edges in parallel: 4 lane-groups of 16, each lane
// loads uint4 (16B) of its group's source row => 1KB per load instruction.
// shfl_xor(16/32) combines groups; lanes 0-15 add self row and store.
__global__ __launch_bounds__(256) void aggregate_bf16(const unsigned short* __restrict__ H,
                                                      const int* __restrict__ rp,
                                                      const int2* __restrict__ csr,
                                                      unsigned short* __restrict__ Out, int n) {
    const int node = blockIdx.x * 4 + (threadIdx.x >> 6);
    const int lane = threadIdx.x & 63;
    if (node >= n) return;
    const int qid   = lane >> 4;      // edge slot within group-of-4
    const int qlane = lane & 15;      // 16B chunk within row
    const uint4* H4 = (const uint4*)H;

    uint4 self = H4[(size_t)node * 16 + qlane];   // issued early, used at end

    float acc[8];
#pragma unroll
    for (int i = 0; i < 8; i++) acc[i] = 0.f;

    const int e0 = rp[node], e1 = rp[node + 1];
    for (int base = e0; base < e1; base += 64) {
        const int cnt = min(64, e1 - base);
        int   sv = 0;
        float wv = 0.f;
        if (base + lane < e1) {
            int2 p = csr[base + lane];
            sv = p.x & 0x1FFFF;
            wv = __int_as_float(p.y);
        }
        const int g4 = (cnt + 3) >> 2;
#pragma unroll 2
        for (int jg = 0; jg < g4; jg++) {
            int   j  = jg * 4 + qid;
            int   sj = __shfl(sv, j);
            float wj = __shfl(wv, j);      // 0 for tail slots -> no contribution
            uint4 v  = H4[(size_t)sj * 16 + qlane];
            acc[0] += wj * bflo(v.x); acc[1] += wj * bfhi(v.x);
            acc[2] += wj * bflo(v.y); acc[3] += wj * bfhi(v.y);
            acc[4] += wj * bflo(v.z); acc[5] += wj * bfhi(v.z);
            acc[6] += wj * bflo(v.w); acc[7] += wj * bfhi(v.w);
        }
    }

    // combine the 4 lane-groups (lane k, k+16, k+32, k+48 hold same features)
#pragma unroll
    for (int i = 0; i < 8; i++) {
        acc[i] += __shfl_xor(acc[i], 16);
        acc[i] += __shfl_xor(acc[i], 32);
    }

    if (qid == 0) {
        acc[0] += bflo(self.x); acc[1] += bfhi(self.x);
        acc[2] += bflo(self.y); acc[3] += bfhi(self.y);
        acc[4] += bflo(self.z); acc[5] += bfhi(self.z);
        acc[6] += bflo(self.w); acc[7] += bfhi(self.w);
        uint4 o;
        o.x = packbf(acc[0], acc[1]);
        o.y = packbf(acc[2], acc[3]);
        o.z = packbf(acc[4], acc[5]);
        o.w = packbf(acc[6], acc[7]);
        ((uint4*)Out)[(size_t)node * 16 + qlane] = o;
    }
}

// ---- MFMA GEMM: Out[N,128] = relu(A[N,128] @ W + b), bf16 in/out ----------
__global__ __launch_bounds__(256) void gemm_mfma_bias_relu(const unsigned short* __restrict__ A,
                                                           const unsigned short* __restrict__ Wp,
                                                           const float* __restrict__ bias,
                                                           unsigned short* __restrict__ Out,
                                                           int nrows) {
    const int wave = threadIdx.x >> 6;
    const int lane = threadIdx.x & 63;
    const int rbase = blockIdx.x * 64 + wave * 16;
    const int arow = rbase + (lane & 15);
    const int arow_c = min(arow, nrows - 1);

    const short8* Arow = (const short8*)(A + (size_t)arow_c * 128);
    short8 a[4];
#pragma unroll
    for (int kg = 0; kg < 4; kg++) a[kg] = Arow[kg * 4 + (lane >> 4)];

    const short8* Bp = (const short8*)Wp;
    const int drow = rbase + ((lane >> 4) << 2);
    const int dcol = lane & 15;
#pragma unroll
    for (int cf = 0; cf < 8; cf++) {
        f32x4 acc = {0.f, 0.f, 0.f, 0.f};
#pragma unroll
        for (int kg = 0; kg < 4; kg++) {
            short8 b = Bp[(cf * 4 + kg) * 64 + lane];
            acc = __builtin_amdgcn_mfma_f32_16x16x32_bf16(a[kg], b, acc, 0, 0, 0);
        }
        float bv = bias[cf * 16 + dcol];
#pragma unroll
        for (int i = 0; i < 4; i++) {
            int r = drow + i;
            if (r < nrows) {
                float v = fmaxf(acc[i] + bv, 0.f);
                Out[(size_t)r * 128 + cf * 16 + dcol] = f2bf(v);
            }
        }
    }
}

// ---- pooling ---------------------------------------------------------------
__global__ __launch_bounds__(256) void graph_count(const int* __restrict__ batch,
                                                   int* __restrict__ cnt, int n) {
    int t  = blockIdx.x * 256 + threadIdx.x;
    int i0 = t * 16;
    if (i0 >= n) return;
    int end = min(i0 + 16, n);
    int g = batch[i0], c = 0;
    for (int i = i0; i < end; i++) {
        int gi = batch[i];
        if (gi != g) { atomicAdd(&cnt[g], c); g = gi; c = 0; }
        c++;
    }
    atomicAdd(&cnt[g], c);
}

__global__ __launch_bounds__(128) void pool_nodes(const unsigned short* __restrict__ H,
                                                  const int* __restrict__ batch,
                                                  float* __restrict__ P, int n) {
    int k     = threadIdx.x;
    int start = blockIdx.x * 256;
    int end   = min(start + 256, n);
    float acc = 0.f;
    int gcur  = batch[start];
    for (int i = start; i < end; i++) {
        int g = batch[i];
        if (g != gcur) { atomicAdd(&P[gcur * 128 + k], acc); acc = 0.f; gcur = g; }
        acc += bf2f(H[(size_t)i * 128 + k]);
    }
    atomicAdd(&P[gcur * 128 + k], acc);
}

__global__ __launch_bounds__(256) void final_kernel(const float* __restrict__ P,
                                                    const float* __restrict__ W3,
                                                    const float* __restrict__ b3,
                                                    const int* __restrict__ cnt,
                                                    float* __restrict__ out, int total) {
    int idx = blockIdx.x * 256 + threadIdx.x;
    if (idx >= total) return;
    int g = idx / 40, c = idx % 40;
    float acc = (float)cnt[g] * b3[c];
    for (int kk = 0; kk < 128; kk++) acc += P[g * 128 + kk] * W3[kk * 40 + c];
    out[idx] = acc;
}

// ---------------------------------------------------------------------------
extern "C" void kernel_launch(void* const* d_in, const int* in_sizes, int n_in,
                              void* d_out, int out_size, void* d_ws, size_t ws_size,
                              hipStream_t stream) {
    const float* x     = (const float*)d_in[0];
    const int*   ei    = (const int*)d_in[1];
    const float* ew    = (const float*)d_in[2];
    const int*   batch = (const int*)d_in[3];
    const float* W1    = (const float*)d_in[4];
    const float* b1    = (const float*)d_in[5];
    const float* W2    = (const float*)d_in[6];
    const float* b2    = (const float*)d_in[7];
    const float* W3    = (const float*)d_in[8];
    const float* b3    = (const float*)d_in[9];
    float*       out   = (float*)d_out;

    const int E_ = in_sizes[2];   // edge_weight length
    const int N_ = in_sizes[3];   // batch length  (N_ < 131072 for 17-bit src pack)
    const int* srcp = ei;
    const int* dstp = ei + E_;
    const int NB = (N_ + BKT_NODES - 1) >> BKT_SHIFT;

    char*  w   = (char*)d_ws;
    size_t off = 0;
    auto take = [&](size_t bytes) -> char* {
        char* p = w + off;
        off = (off + bytes + 255) & ~(size_t)255;
        return p;
    };
    unsigned short* xb  = (unsigned short*)take((size_t)N_ * 128 * 2);
    unsigned short* Ha  = (unsigned short*)take((size_t)N_ * 128 * 2);
    unsigned short* Hb  = (unsigned short*)take((size_t)N_ * 128 * 2);
    int*   rp      = (int*)take((size_t)(N_ + 1) * 4);
    uint2* tempE   = (uint2*)take((size_t)E_ * 8);
    uint2* csr     = (uint2*)take((size_t)E_ * 8);
    int*   bh      = (int*)take(512 * 4);
    int*   bstart  = (int*)take(513 * 4);
    int*   gcur    = (int*)take(512 * 4);
    float* P       = (float*)take(64 * 128 * 4);
    int*   cnt     = (int*)take(64 * 4);
    unsigned short* W1p = (unsigned short*)take(16384 * 2);
    unsigned short* W2p = (unsigned short*)take(16384 * 2);
    (void)ws_size; (void)n_in;

    // ---- CSR build via bucketed counting sort (all writes coalesced) ----
    hipMemsetAsync(bh, 0, 512 * 4, stream);
    bucket_hist<<<1024, 256, 0, stream>>>(dstp, bh, E_);
    bucket_scan<<<1, 512, 0, stream>>>(bh, bstart, gcur, rp, NB, N_, E_);
    partition_edges<<<(E_ + PCHUNK - 1) / PCHUNK, 256, 0, stream>>>(srcp, dstp, ew,
                                                                    gcur, tempE, E_);
    sort_bucket<<<NB, 256, 0, stream>>>(tempE, bstart, csr, rp, N_);

    // bf16 conversions / weight packing
    convert_bf16<<<(N_ * 16 + 255) / 256, 256, 0, stream>>>(x, xb, N_ * 16);
    pack_w<<<64, 256, 0, stream>>>(W1, W1p);
    pack_w<<<64, 256, 0, stream>>>(W2, W2p);

    const int agrid = (N_ + 3) / 4;
    const int ggrid = (N_ + 63) / 64;
    // layer 1
    aggregate_bf16<<<agrid, 256, 0, stream>>>(xb, rp, (const int2*)csr, Ha, N_);
    gemm_mfma_bias_relu<<<ggrid, 256, 0, stream>>>(Ha, W1p, b1, Hb, N_);
    // layer 2
    aggregate_bf16<<<agrid, 256, 0, stream>>>(Hb, rp, (const int2*)csr, Ha, N_);
    gemm_mfma_bias_relu<<<ggrid, 256, 0, stream>>>(Ha, W2p, b2, Hb, N_);
    // layer 3 aggregate (h2 + agg3), then pooled path
    aggregate_bf16<<<agrid, 256, 0, stream>>>(Hb, rp, (const int2*)csr, Ha, N_);

    hipMemsetAsync(P, 0, 64 * 128 * 4, stream);
    hipMemsetAsync(cnt, 0, 64 * 4, stream);
    graph_count<<<((N_ + 15) / 16 + 255) / 256, 256, 0, stream>>>(batch, cnt, N_);
    pool_nodes<<<(N_ + 255) / 256, 128, 0, stream>>>(Ha, batch, P, N_);
    final_kernel<<<(out_size + 255) / 256, 256, 0, stream>>>(P, W3, b3, cnt, out, out_size);
}

// Round 8
// 366.157 us; speedup vs baseline: 16.0591x; 1.1516x over previous
//
#include <hip/hip_runtime.h>

// ---------------------------------------------------------------------------
// GIN forward, bf16 internal storage. 3x { agg = h + scatter(w*h[src]);
// h = relu(agg@W+b) }, layer3+pool fused: out[g]=pool_g(h2+agg3)@W3+cnt*b3.
// CSR built by bucketed counting sort (R5). Aggregate: 4-edge-parallel wave
// gather (R6). Pool: 4-wave/block run-length reduce (R7: old version was
// 7.8% occupancy, 71us; latency-bound not BW-bound).
// ---------------------------------------------------------------------------

typedef __attribute__((ext_vector_type(8))) short short8;
typedef __attribute__((ext_vector_type(4))) float f32x4;

__device__ __forceinline__ unsigned short f2bf(float f) {
    unsigned u = __builtin_bit_cast(unsigned, f);
    u += 0x7fff + ((u >> 16) & 1);           // RNE
    return (unsigned short)(u >> 16);
}
__device__ __forceinline__ float bf2f(unsigned short s) {
    unsigned u = (unsigned)s << 16;
    return __builtin_bit_cast(float, u);
}
__device__ __forceinline__ float bflo(unsigned u) {
    return __builtin_bit_cast(float, u << 16);
}
__device__ __forceinline__ float bfhi(unsigned u) {
    return __builtin_bit_cast(float, u & 0xffff0000u);
}
__device__ __forceinline__ unsigned packbf(float a, float b) {
    return (unsigned)f2bf(a) | ((unsigned)f2bf(b) << 16);
}

#define BKT_SHIFT 8
#define BKT_NODES 256            // nodes per bucket; NB <= 512 (N < 131072)
#define PCHUNK 4096              // edges per partition block
#define SB_CAP 7168              // max edges per bucket in sort LDS

// ---- bucket-level histogram (LDS-aggregated, coalesced reads) -------------
__global__ __launch_bounds__(256) void bucket_hist(const int* __restrict__ dst,
                                                   int* __restrict__ bh, int E_) {
    __shared__ int lh[512];
    for (int i = threadIdx.x; i < 512; i += 256) lh[i] = 0;
    __syncthreads();
    for (int i = blockIdx.x * 256 + threadIdx.x; i < E_; i += gridDim.x * 256)
        atomicAdd(&lh[dst[i] >> BKT_SHIFT], 1);
    __syncthreads();
    for (int i = threadIdx.x; i < 512; i += 256)
        if (lh[i]) atomicAdd(&bh[i], lh[i]);
}

// ---- bucket scan: bstart (exclusive), gcursor init, rp[N]=E ---------------
__global__ __launch_bounds__(512) void bucket_scan(const int* __restrict__ bh,
                                                   int* __restrict__ bstart,
                                                   int* __restrict__ gcur,
                                                   int* __restrict__ rp,
                                                   int NB, int N_, int E_) {
    __shared__ int sd[512];
    const int tid = threadIdx.x;
    int v = (tid < NB) ? bh[tid] : 0;
    sd[tid] = v;
    __syncthreads();
    for (int ofs = 1; ofs < 512; ofs <<= 1) {
        int t = (tid >= ofs) ? sd[tid - ofs] : 0;
        __syncthreads();
        sd[tid] += t;
        __syncthreads();
    }
    int excl = sd[tid] - v;
    if (tid < NB) { bstart[tid] = excl; gcur[tid] = excl; }
    if (tid == NB - 1) bstart[NB] = excl + v;   // == E_
    if (tid == 0) rp[N_] = E_;
}

// ---- partition edges into bucket regions (coalesced run writes) -----------
__global__ __launch_bounds__(256) void partition_edges(const int* __restrict__ src,
                                                       const int* __restrict__ dst,
                                                       const float* __restrict__ ew,
                                                       int* __restrict__ gcur,
                                                       uint2* __restrict__ temp, int E_) {
    __shared__ int lcur[512];
    __shared__ int lexcl[512];
    __shared__ int gbase[512];
    __shared__ unsigned short bof[PCHUNK];
    __shared__ uint2 stag[PCHUNK];
    __shared__ int sd[256];
    const int tid = threadIdx.x;
    const int e0  = blockIdx.x * PCHUNK;
    const int n   = min(PCHUNK, E_ - e0);

    for (int i = tid; i < 512; i += 256) lcur[i] = 0;
    __syncthreads();
    for (int i = tid; i < n; i += 256)
        atomicAdd(&lcur[dst[e0 + i] >> BKT_SHIFT], 1);
    __syncthreads();
    const int a0 = lcur[2 * tid], a1 = lcur[2 * tid + 1];
    const int ps = a0 + a1;
    sd[tid] = ps;
    __syncthreads();
    for (int ofs = 1; ofs < 256; ofs <<= 1) {
        int t = (tid >= ofs) ? sd[tid - ofs] : 0;
        __syncthreads();
        sd[tid] += t;
        __syncthreads();
    }
    const int pexcl = sd[tid] - ps;
    __syncthreads();
    lexcl[2 * tid] = pexcl;      lexcl[2 * tid + 1] = pexcl + a0;
    lcur [2 * tid] = pexcl;      lcur [2 * tid + 1] = pexcl + a0;
    __syncthreads();
    for (int i = tid; i < n; i += 256) {
        int   s = src[e0 + i], d = dst[e0 + i];
        float wv = ew[e0 + i];
        int b = d >> BKT_SHIFT;
        int p = atomicAdd(&lcur[b], 1);
        stag[p].x = (unsigned)s | ((unsigned)(d & (BKT_NODES - 1)) << 17);
        stag[p].y = __float_as_uint(wv);
        bof[p] = (unsigned short)b;
    }
    __syncthreads();
    if (a0) gbase[2 * tid]     = atomicAdd(&gcur[2 * tid],     a0);
    if (a1) gbase[2 * tid + 1] = atomicAdd(&gcur[2 * tid + 1], a1);
    __syncthreads();
    for (int i = tid; i < n; i += 256) {
        int b = bof[i];
        temp[gbase[b] + (i - lexcl[b])] = stag[i];
    }
}

// ---- per-bucket counting sort by dst low bits; writes csr + rp ------------
__global__ __launch_bounds__(256) void sort_bucket(const uint2* __restrict__ temp,
                                                   const int* __restrict__ bstart,
                                                   uint2* __restrict__ csr,
                                                   int* __restrict__ rp, int N_) {
    __shared__ int h[256], hcur[256], sd[256];
    __shared__ uint2 outb[SB_CAP];
    const int b = blockIdx.x, tid = threadIdx.x;
    const int lo = bstart[b], hi = bstart[b + 1];
    const int L = hi - lo;
    h[tid] = 0;
    __syncthreads();
    for (int i = tid; i < L; i += 256)
        atomicAdd(&h[(temp[lo + i].x >> 17) & (BKT_NODES - 1)], 1);
    __syncthreads();
    int v = h[tid];
    sd[tid] = v;
    __syncthreads();
    for (int ofs = 1; ofs < 256; ofs <<= 1) {
        int t = (tid >= ofs) ? sd[tid - ofs] : 0;
        __syncthreads();
        sd[tid] += t;
        __syncthreads();
    }
    const int excl = sd[tid] - v;
    hcur[tid] = excl;
    const int node = b * BKT_NODES + tid;
    if (node <= N_) rp[node] = lo + excl;
    __syncthreads();
    for (int i = tid; i < L; i += 256) {
        uint2 p = temp[lo + i];
        int pos = atomicAdd(&hcur[(p.x >> 17) & (BKT_NODES - 1)], 1);
        outb[pos] = p;
    }
    __syncthreads();
    for (int i = tid; i < L; i += 256) csr[lo + i] = outb[i];
}

// ---- f32 -> bf16 row conversion (for x) -----------------------------------
__global__ __launch_bounds__(256) void convert_bf16(const float* __restrict__ in,
                                                    unsigned short* __restrict__ out, int n8) {
    int i = blockIdx.x * 256 + threadIdx.x;
    if (i >= n8) return;
    const float4* in4 = (const float4*)in;
    float4 a = in4[(size_t)i * 2], b = in4[(size_t)i * 2 + 1];
    short8 o;
    o[0] = (short)f2bf(a.x); o[1] = (short)f2bf(a.y);
    o[2] = (short)f2bf(a.z); o[3] = (short)f2bf(a.w);
    o[4] = (short)f2bf(b.x); o[5] = (short)f2bf(b.y);
    o[6] = (short)f2bf(b.z); o[7] = (short)f2bf(b.w);
    ((short8*)out)[i] = o;
}

// ---- W pack: f32 [128][128] -> bf16 fragment order [cf][kg][lane][8] ------
__global__ __launch_bounds__(256) void pack_w(const float* __restrict__ W,
                                              unsigned short* __restrict__ Wp) {
    int idx = blockIdx.x * 256 + threadIdx.x;        // 0..16383
    int j = idx & 7, lane = (idx >> 3) & 63, kg = (idx >> 9) & 3, cf = idx >> 11;
    int k = kg * 32 + ((lane >> 4) & 3) * 8 + j;
    int c = cf * 16 + (lane & 15);
    Wp[idx] = f2bf(W[k * 128 + c]);
}

// ---- aggregation (bf16 rows): Out[n] = H[n] + sum w_e * H[src_e] ----------
// One wave per node, 4 edges in parallel: 4 lane-groups of 16, each lane
// loads uint4 (16B) of its group's source row => 1KB per load instruction.
__global__ __launch_bounds__(256) void aggregate_bf16(const unsigned short* __restrict__ H,
                                                      const int* __restrict__ rp,
                                                      const int2* __restrict__ csr,
                                                      unsigned short* __restrict__ Out, int n) {
    const int node = blockIdx.x * 4 + (threadIdx.x >> 6);
    const int lane = threadIdx.x & 63;
    if (node >= n) return;
    const int qid   = lane >> 4;      // edge slot within group-of-4
    const int qlane = lane & 15;      // 16B chunk within row
    const uint4* H4 = (const uint4*)H;

    uint4 self = H4[(size_t)node * 16 + qlane];   // issued early, used at end

    float acc[8];
#pragma unroll
    for (int i = 0; i < 8; i++) acc[i] = 0.f;

    const int e0 = rp[node], e1 = rp[node + 1];
    for (int base = e0; base < e1; base += 64) {
        const int cnt = min(64, e1 - base);
        int   sv = 0;
        float wv = 0.f;
        if (base + lane < e1) {
            int2 p = csr[base + lane];
            sv = p.x & 0x1FFFF;
            wv = __int_as_float(p.y);
        }
        const int g4 = (cnt + 3) >> 2;
#pragma unroll 2
        for (int jg = 0; jg < g4; jg++) {
            int   j  = jg * 4 + qid;
            int   sj = __shfl(sv, j);
            float wj = __shfl(wv, j);      // 0 for tail slots -> no contribution
            uint4 v  = H4[(size_t)sj * 16 + qlane];
            acc[0] += wj * bflo(v.x); acc[1] += wj * bfhi(v.x);
            acc[2] += wj * bflo(v.y); acc[3] += wj * bfhi(v.y);
            acc[4] += wj * bflo(v.z); acc[5] += wj * bfhi(v.z);
            acc[6] += wj * bflo(v.w); acc[7] += wj * bfhi(v.w);
        }
    }

    // combine the 4 lane-groups (lane k, k+16, k+32, k+48 hold same features)
#pragma unroll
    for (int i = 0; i < 8; i++) {
        acc[i] += __shfl_xor(acc[i], 16);
        acc[i] += __shfl_xor(acc[i], 32);
    }

    if (qid == 0) {
        acc[0] += bflo(self.x); acc[1] += bfhi(self.x);
        acc[2] += bflo(self.y); acc[3] += bfhi(self.y);
        acc[4] += bflo(self.z); acc[5] += bfhi(self.z);
        acc[6] += bflo(self.w); acc[7] += bfhi(self.w);
        uint4 o;
        o.x = packbf(acc[0], acc[1]);
        o.y = packbf(acc[2], acc[3]);
        o.z = packbf(acc[4], acc[5]);
        o.w = packbf(acc[6], acc[7]);
        ((uint4*)Out)[(size_t)node * 16 + qlane] = o;
    }
}

// ---- MFMA GEMM: Out[N,128] = relu(A[N,128] @ W + b), bf16 in/out ----------
__global__ __launch_bounds__(256) void gemm_mfma_bias_relu(const unsigned short* __restrict__ A,
                                                           const unsigned short* __restrict__ Wp,
                                                           const float* __restrict__ bias,
                                                           unsigned short* __restrict__ Out,
                                                           int nrows) {
    const int wave = threadIdx.x >> 6;
    const int lane = threadIdx.x & 63;
    const int rbase = blockIdx.x * 64 + wave * 16;
    const int arow = rbase + (lane & 15);
    const int arow_c = min(arow, nrows - 1);

    const short8* Arow = (const short8*)(A + (size_t)arow_c * 128);
    short8 a[4];
#pragma unroll
    for (int kg = 0; kg < 4; kg++) a[kg] = Arow[kg * 4 + (lane >> 4)];

    const short8* Bp = (const short8*)Wp;
    const int drow = rbase + ((lane >> 4) << 2);
    const int dcol = lane & 15;
#pragma unroll
    for (int cf = 0; cf < 8; cf++) {
        f32x4 acc = {0.f, 0.f, 0.f, 0.f};
#pragma unroll
        for (int kg = 0; kg < 4; kg++) {
            short8 b = Bp[(cf * 4 + kg) * 64 + lane];
            acc = __builtin_amdgcn_mfma_f32_16x16x32_bf16(a[kg], b, acc, 0, 0, 0);
        }
        float bv = bias[cf * 16 + dcol];
#pragma unroll
        for (int i = 0; i < 4; i++) {
            int r = drow + i;
            if (r < nrows) {
                float v = fmaxf(acc[i] + bv, 0.f);
                Out[(size_t)r * 128 + cf * 16 + dcol] = f2bf(v);
            }
        }
    }
}

// ---- pooling ---------------------------------------------------------------
__global__ __launch_bounds__(256) void graph_count(const int* __restrict__ batch,
                                                   int* __restrict__ cnt, int n) {
    int t  = blockIdx.x * 256 + threadIdx.x;
    int i0 = t * 16;
    if (i0 >= n) return;
    int end = min(i0 + 16, n);
    int g = batch[i0], c = 0;
    for (int i = i0; i < end; i++) {
        int gi = batch[i];
        if (gi != g) { atomicAdd(&cnt[g], c); g = gi; c = 0; }
        c++;
    }
    atomicAdd(&cnt[g], c);
}

// P[g][k] += sum_{n in g} H[n][k]. 64-row chunk per block, 4 waves; wave w
// visits rows start+w, start+w+4, ... (monotone under sorted batch -> exact
// run-length flush). Lane owns a feature pair (uint): coalesced 256B/row.
__global__ __launch_bounds__(256) void pool_nodes(const unsigned short* __restrict__ H,
                                                  const int* __restrict__ batch,
                                                  float* __restrict__ P, int n) {
    const int k2 = threadIdx.x & 63;        // feature pair
    const int wv = threadIdx.x >> 6;        // wave = row stride phase
    int r = blockIdx.x * 64 + wv;
    const int end = min(blockIdx.x * 64 + 64, n);
    if (r >= end) return;
    const unsigned* H32 = (const unsigned*)H;
    float ax = 0.f, ay = 0.f;
    int gcur = batch[r];
    for (; r < end; r += 4) {
        int g = batch[r];                    // wave-uniform scalar load
        if (g != gcur) {
            atomicAdd(&P[gcur * 128 + 2 * k2], ax);
            atomicAdd(&P[gcur * 128 + 2 * k2 + 1], ay);
            ax = ay = 0.f;
            gcur = g;
        }
        unsigned v = H32[(size_t)r * 64 + k2];
        ax += bflo(v);
        ay += bfhi(v);
    }
    atomicAdd(&P[gcur * 128 + 2 * k2], ax);
    atomicAdd(&P[gcur * 128 + 2 * k2 + 1], ay);
}

__global__ __launch_bounds__(256) void final_kernel(const float* __restrict__ P,
                                                    const float* __restrict__ W3,
                                                    const float* __restrict__ b3,
                                                    const int* __restrict__ cnt,
                                                    float* __restrict__ out, int total) {
    int idx = blockIdx.x * 256 + threadIdx.x;
    if (idx >= total) return;
    int g = idx / 40, c = idx % 40;
    float acc = (float)cnt[g] * b3[c];
    for (int kk = 0; kk < 128; kk++) acc += P[g * 128 + kk] * W3[kk * 40 + c];
    out[idx] = acc;
}

// ---------------------------------------------------------------------------
extern "C" void kernel_launch(void* const* d_in, const int* in_sizes, int n_in,
                              void* d_out, int out_size, void* d_ws, size_t ws_size,
                              hipStream_t stream) {
    const float* x     = (const float*)d_in[0];
    const int*   ei    = (const int*)d_in[1];
    const float* ew    = (const float*)d_in[2];
    const int*   batch = (const int*)d_in[3];
    const float* W1    = (const float*)d_in[4];
    const float* b1    = (const float*)d_in[5];
    const float* W2    = (const float*)d_in[6];
    const float* b2    = (const float*)d_in[7];
    const float* W3    = (const float*)d_in[8];
    const float* b3    = (const float*)d_in[9];
    float*       out   = (float*)d_out;

    const int E_ = in_sizes[2];   // edge_weight length
    const int N_ = in_sizes[3];   // batch length  (N_ < 131072 for 17-bit src pack)
    const int* srcp = ei;
    const int* dstp = ei + E_;
    const int NB = (N_ + BKT_NODES - 1) >> BKT_SHIFT;

    char*  w   = (char*)d_ws;
    size_t off = 0;
    auto take = [&](size_t bytes) -> char* {
        char* p = w + off;
        off = (off + bytes + 255) & ~(size_t)255;
        return p;
    };
    unsigned short* xb  = (unsigned short*)take((size_t)N_ * 128 * 2);
    unsigned short* Ha  = (unsigned short*)take((size_t)N_ * 128 * 2);
    unsigned short* Hb  = (unsigned short*)take((size_t)N_ * 128 * 2);
    int*   rp      = (int*)take((size_t)(N_ + 1) * 4);
    uint2* tempE   = (uint2*)take((size_t)E_ * 8);
    uint2* csr     = (uint2*)take((size_t)E_ * 8);
    int*   bh      = (int*)take(512 * 4);
    int*   bstart  = (int*)take(513 * 4);
    int*   gcur    = (int*)take(512 * 4);
    float* P       = (float*)take(64 * 128 * 4);
    int*   cnt     = (int*)take(64 * 4);
    unsigned short* W1p = (unsigned short*)take(16384 * 2);
    unsigned short* W2p = (unsigned short*)take(16384 * 2);
    (void)ws_size; (void)n_in;

    // ---- CSR build via bucketed counting sort (all writes coalesced) ----
    hipMemsetAsync(bh, 0, 512 * 4, stream);
    bucket_hist<<<1024, 256, 0, stream>>>(dstp, bh, E_);
    bucket_scan<<<1, 512, 0, stream>>>(bh, bstart, gcur, rp, NB, N_, E_);
    partition_edges<<<(E_ + PCHUNK - 1) / PCHUNK, 256, 0, stream>>>(srcp, dstp, ew,
                                                                    gcur, tempE, E_);
    sort_bucket<<<NB, 256, 0, stream>>>(tempE, bstart, csr, rp, N_);

    // bf16 conversions / weight packing
    convert_bf16<<<(N_ * 16 + 255) / 256, 256, 0, stream>>>(x, xb, N_ * 16);
    pack_w<<<64, 256, 0, stream>>>(W1, W1p);
    pack_w<<<64, 256, 0, stream>>>(W2, W2p);

    const int agrid = (N_ + 3) / 4;
    const int ggrid = (N_ + 63) / 64;
    // layer 1
    aggregate_bf16<<<agrid, 256, 0, stream>>>(xb, rp, (const int2*)csr, Ha, N_);
    gemm_mfma_bias_relu<<<ggrid, 256, 0, stream>>>(Ha, W1p, b1, Hb, N_);
    // layer 2
    aggregate_bf16<<<agrid, 256, 0, stream>>>(Hb, rp, (const int2*)csr, Ha, N_);
    gemm_mfma_bias_relu<<<ggrid, 256, 0, stream>>>(Ha, W2p, b2, Hb, N_);
    // layer 3 aggregate (h2 + agg3), then pooled path
    aggregate_bf16<<<agrid, 256, 0, stream>>>(Hb, rp, (const int2*)csr, Ha, N_);

    hipMemsetAsync(P, 0, 64 * 128 * 4, stream);
    hipMemsetAsync(cnt, 0, 64 * 4, stream);
    graph_count<<<((N_ + 15) / 16 + 255) / 256, 256, 0, stream>>>(batch, cnt, N_);
    pool_nodes<<<(N_ + 63) / 64, 256, 0, stream>>>(Ha, batch, P, N_);
    final_kernel<<<(out_size + 255) / 256, 256, 0, stream>>>(P, W3, b3, cnt, out, out_size);
}